// Round 2
// baseline (371.655 us; speedup 1.0000x reference)
//
#include <hip/hip_runtime.h>
#include <hip/hip_bf16.h>

typedef __hip_bfloat16 bf16;
typedef __bf16 bf16x8 __attribute__((ext_vector_type(8)));
typedef __bf16 bf16x4 __attribute__((ext_vector_type(4)));
typedef float  f32x4  __attribute__((ext_vector_type(4)));

constexpr int NB   = 4;
constexpr int H    = 128;
constexpr int W    = 128;
constexpr int HW   = H * W;
constexpr int NPIX = NB * HW;        // 65536
constexpr int CCAT = 384;
constexpr int CSKIP= 128;
constexpr int CIN  = 256;
constexpr int CO   = 128;
constexpr int HS   = 64;
constexpr int WP   = 130;            // padded H/W
constexpr int K1   = 3456;           // conv1 GEMM K
constexpr int KD   = 1152;           // deform/off GEMM K
constexpr int NBORD= 2 * WP + 2 * (WP - 2);   // 516 border px per image
constexpr float EPS = 1e-5f;

__device__ __forceinline__ float b2f(bf16 v){ return __bfloat162float(v); }
__device__ __forceinline__ bf16  f2b(float v){ return __float2bfloat16(v); }

__device__ __forceinline__ void async_copy16(const void* g, void* s){
    __builtin_amdgcn_global_load_lds((const __attribute__((address_space(1))) void*)g,
                                     (__attribute__((address_space(3))) void*)s, 16, 0, 0);
}

// map border index 0..515 -> (y,x) on the WPxWP frame
__device__ __forceinline__ void border_yx(int p, int& y, int& x){
    if (p < WP)             { y = 0;        x = p; }
    else if (p < 2 * WP)    { y = WP - 1;   x = p - WP; }
    else if (p < 2 * WP + (WP - 2)) { y = p - 2 * WP + 1;          x = 0; }
    else                    { y = p - (2 * WP + (WP - 2)) + 1;     x = WP - 1; }
}

// ------------- prep: zero stat buffers + padded borders -------------
__global__ void k_prep(float* __restrict__ sums, bf16* __restrict__ catp,
                       bf16* __restrict__ hp){
    int i = blockIdx.x * blockDim.x + threadIdx.x;
    int stride = gridDim.x * blockDim.x;
    for (int j = i; j < 512; j += stride) sums[j] = 0.f;
    const int nCat = NB * NBORD * CCAT;
    for (int j = i; j < nCat; j += stride){
        int c = j % CCAT, r = j / CCAT, p = r % NBORD, b = r / NBORD;
        int y, x; border_yx(p, y, x);
        catp[(((size_t)b * WP + y) * WP + x) * CCAT + c] = f2b(0.f);
    }
    const int nHp = NB * NBORD * CO;
    for (int j = i; j < nHp; j += stride){
        int c = j % CO, r = j / CO, p = r % NBORD, b = r / NBORD;
        int y, x; border_yx(p, y, x);
        hp[(((size_t)b * WP + y) * WP + x) * CO + c] = f2b(0.f);
    }
}

// ------------- build cat interior via LDS transpose -------------
__global__ __launch_bounds__(256) void k_build_cat2(const float* __restrict__ x,
                                                    const float* __restrict__ skip,
                                                    bf16* __restrict__ catp){
    constexpr int TS = 66;
    __shared__ bf16 tile[128 * TS];
    int t  = threadIdx.x;
    int y  = blockIdx.x % H, b = blockIdx.x / H;
    int xx = t & 127, cp = t >> 7;

    float cy = (y * 63.0f) / 127.0f;
    int   y0 = (int)cy;
    int   y1 = min(y0 + 1, HS - 1);
    float wy = cy - y0;
    float cxf = (xx * 63.0f) / 127.0f;
    int   x0 = (int)cxf;
    int   x1 = min(x0 + 1, HS - 1);
    float wx = cxf - x0;

    bf16* orow = catp + (((size_t)b * WP + y + 1) * WP + 1) * CCAT;

    for (int chunk = 0; chunk < 6; chunk++){
        int cbase = chunk * 64;
        if (chunk >= 1) __syncthreads();
        if (chunk < 2){
            const float* sb = skip + ((size_t)(b * CSKIP + cbase + cp * 32) * H + y) * W;
#pragma unroll
            for (int i = 0; i < 32; i++)
                tile[xx * TS + cp * 32 + i] = f2b(sb[(size_t)i * HW + xx]);
        } else {
            int icb = (chunk - 2) * 64 + cp * 32;
            const float* xr0 = x + ((size_t)(b * CIN + icb) * HS + y0) * HS;
            const float* xr1 = x + ((size_t)(b * CIN + icb) * HS + y1) * HS;
#pragma unroll
            for (int i = 0; i < 32; i++){
                const float* r0 = xr0 + (size_t)i * HS * HS;
                const float* r1 = xr1 + (size_t)i * HS * HS;
                float v0 = r0[x0] * (1 - wx) + r0[x1] * wx;
                float v1 = r1[x0] * (1 - wx) + r1[x1] * wx;
                tile[xx * TS + cp * 32 + i] = f2b(v0 * (1 - wy) + v1 * wy);
            }
        }
        __syncthreads();
        int cc2 = (t & 31) * 2;
        int px0 = t >> 5;
#pragma unroll
        for (int pp = 0; pp < 16; pp++){
            int px = pp * 8 + px0;
            unsigned int v = *(const unsigned int*)&tile[px * TS + cc2];
            *(unsigned int*)&orow[(size_t)px * CCAT + cbase + cc2] = v;
        }
    }
}

// ------------- all weight transposes in one kernel -------------
__global__ void k_tr_all(const float* __restrict__ w1, const float* __restrict__ wo,
                         const float* __restrict__ wd,
                         bf16* __restrict__ wt1, bf16* __restrict__ wto,
                         bf16* __restrict__ wtd){
    int i = blockIdx.x * blockDim.x + threadIdx.x;
    if (i < CO * K1){
        int k = i % K1, oc = i / K1;
        int ky = k / 1152, r = k % 1152, kx = r / 384, ic = r % 384;
        wt1[i] = f2b(w1[((oc * CCAT + ic) * 3 + ky) * 3 + kx]);
        return;
    }
    i -= CO * K1;
    if (i < 32 * KD){
        int kk = i % KD, o = i / KD;
        int ky = kk / 384, r = kk % 384, kx = r >> 7, ic = r & 127;
        wto[i] = (o < 18) ? f2b(wo[((o * CO + ic) * 3 + ky) * 3 + kx]) : f2b(0.f);
        return;
    }
    i -= 32 * KD;
    if (i < CO * KD){
        int kk = i % KD, o = i / KD;
        int kp = kk >> 7, c = kk & 127;
        wtd[i] = f2b(wd[(o * CO + c) * 9 + kp]);
    }
}

// ------------- conv1: counted-vmcnt pipelined MFMA (T3+T4+T5) -------------
// 54 phases p=(ky*3+ci)*6 + kx*2 + s64. Ab double-buffered per group g=p/6,
// Bb double-buffered per phase. Per phase: barrier -> issue B(p+1) [+A(g+1)
// at j==1] -> s_waitcnt vmcnt(4|9) (never 0 mid-loop) -> barrier -> MFMA.
// Per-wave load counts are uniform (B:4, A:5 with clamped duplicate chunk)
// so the vmcnt arithmetic is exact. Raw s_barrier avoids the compiler's
// vmcnt(0) drain that __syncthreads() emits.
__global__ __launch_bounds__(256) void k_conv1_mfma(const bf16* __restrict__ catp,
                                                    const bf16* __restrict__ wbt,
                                                    bf16* __restrict__ hp,
                                                    float* __restrict__ sums){
    __shared__ unsigned short Ab[2][68 * 128];   // 2 x 17408 B
    __shared__ unsigned short Bb[2][128 * 64];   // 2 x 16384 B
    __shared__ float ps[256];
    int t = threadIdx.x;
    int l = t & 63, w = t >> 6;
    int half = blockIdx.x & 1;
    int y = (blockIdx.x >> 1) % H, b = blockIdx.x / (2 * H);
    int px0 = half * 64;

    int pr   = l >> 3;
    int koct = (l & 7) ^ pr;
    int m    = l & 15, quad = l >> 4;
    int wm   = w & 1,  wn   = w >> 1;

    f32x4 acc[2][4];
#pragma unroll
    for (int i = 0; i < 2; i++)
#pragma unroll
        for (int j = 0; j < 4; j++) acc[i][j] = f32x4{0.f, 0.f, 0.f, 0.f};

    const size_t rowStride = (size_t)WP * CCAT;

    // ---- prologue: issue A_0 then B_0 (FIFO order matters for vmcnt math) ----
    {
        const bf16* Arow0 = catp + ((size_t)(b * WP) + y) * rowStride + (size_t)px0 * CCAT;
#pragma unroll
        for (int k = 0; k < 5; k++){
            int i = min(w + k * 4, 16);
            int G = i * 64 + l;
            int px = G >> 4, ol = G & 15;
            int osrc = ol ^ (px & 7);
            async_copy16(Arow0 + (size_t)px * CCAT + osrc * 8, &Ab[0][i * 512]);
        }
#pragma unroll
        for (int i = 0; i < 4; i++){
            int ocg = w * 32 + i * 8;
            async_copy16(wbt + (size_t)(ocg + pr) * K1 + koct * 8, &Bb[0][ocg * 64]);
        }
    }

    for (int p = 0; p < 54; p++){
        int g = p / 6;
        int j = p - g * 6;
        int s64 = j & 1, kx = j >> 1;

        __builtin_amdgcn_s_barrier();            // phase p-1 readers done
        __builtin_amdgcn_sched_barrier(0);

        if (p < 53){                              // issue B(p+1)
            int pn = p + 1;
            int gn = pn / 6, jn = pn - gn * 6;
            int kyn = gn / 3, cin = gn - kyn * 3;
            int kgn = kyn * 1152 + (jn >> 1) * 384 + cin * 128 + (jn & 1) * 64;
            int bufn = pn & 1;
#pragma unroll
            for (int i = 0; i < 4; i++){
                int ocg = w * 32 + i * 8;
                async_copy16(wbt + (size_t)(ocg + pr) * K1 + kgn + koct * 8,
                             &Bb[bufn][ocg * 64]);
            }
        }
        if (j == 1 && g < 8){                     // issue A(g+1)
            int gn = g + 1;
            int kyn = gn / 3, cin = gn - kyn * 3;
            const bf16* Arow2 = catp + ((size_t)(b * WP) + y + kyn) * rowStride
                              + (size_t)px0 * CCAT + cin * 128;
#pragma unroll
            for (int k = 0; k < 5; k++){
                int i = min(w + k * 4, 16);
                int G = i * 64 + l;
                int px = G >> 4, ol = G & 15;
                int osrc = ol ^ (px & 7);
                async_copy16(Arow2 + (size_t)px * CCAT + osrc * 8, &Ab[gn & 1][i * 512]);
            }
        }
        // counted wait: B(p) landed; A(g+1)+B(p+1) may stay in flight
        if (p == 53)                              asm volatile("s_waitcnt vmcnt(0)" ::: "memory");
        else if ((j == 1 || j == 2) && g < 8)     asm volatile("s_waitcnt vmcnt(9)" ::: "memory");
        else                                      asm volatile("s_waitcnt vmcnt(4)" ::: "memory");
        __builtin_amdgcn_s_barrier();             // all waves' staging visible
        __builtin_amdgcn_sched_barrier(0);

        const bf16x8* ap = (const bf16x8*)&Ab[g & 1][0];
        const bf16x8* bp = (const bf16x8*)&Bb[p & 1][0];
        __builtin_amdgcn_s_setprio(1);
#pragma unroll
        for (int ks = 0; ks < 2; ks++){
            int s = s64 * 2 + ks;
            bf16x8 af[2], bfr[4];
#pragma unroll
            for (int mi = 0; mi < 2; mi++){
                int pxk = wm * 32 + mi * 16 + m + kx;
                af[mi] = ap[pxk * 16 + ((s * 4 + quad) ^ (pxk & 7))];
            }
#pragma unroll
            for (int ni = 0; ni < 4; ni++){
                int oc = wn * 64 + ni * 16 + m;
                bfr[ni] = bp[oc * 8 + ((ks * 4 + quad) ^ (oc & 7))];
            }
#pragma unroll
            for (int mi = 0; mi < 2; mi++)
#pragma unroll
                for (int ni = 0; ni < 4; ni++)
                    acc[mi][ni] = __builtin_amdgcn_mfma_f32_16x16x32_bf16(
                        af[mi], bfr[ni], acc[mi][ni], 0, 0, 0);
        }
        __builtin_amdgcn_s_setprio(0);
    }

    size_t obase = (((size_t)b * WP + y + 1) * WP + 1 + px0) * CO;
#pragma unroll
    for (int mi = 0; mi < 2; mi++){
        int p0 = wm * 32 + mi * 16 + quad * 4;
#pragma unroll
        for (int ni = 0; ni < 4; ni++){
            int oc = wn * 64 + ni * 16 + m;
#pragma unroll
            for (int r = 0; r < 4; r++)
                hp[obase + (size_t)(p0 + r) * CO + oc] = f2b(acc[mi][ni][r]);
        }
    }
    // fused BN1 stats (shfl quad-reduce -> LDS -> one global atomic per ch)
    ps[t] = 0.f;
    __syncthreads();
#pragma unroll
    for (int ni = 0; ni < 4; ni++){
        int ch = wn * 64 + ni * 16 + m;
        float s = 0.f, q = 0.f;
#pragma unroll
        for (int mi = 0; mi < 2; mi++)
#pragma unroll
            for (int r = 0; r < 4; r++){
                float v = acc[mi][ni][r];
                s += v; q += v * v;
            }
        s += __shfl_xor(s, 16); s += __shfl_xor(s, 32);
        q += __shfl_xor(q, 16); q += __shfl_xor(q, 32);
        if (quad == 0){
            atomicAdd(&ps[ch], s);
            atomicAdd(&ps[128 + ch], q);
        }
    }
    __syncthreads();
    if (t < 128){
        atomicAdd(&sums[t],       ps[t]);
        atomicAdd(&sums[128 + t], ps[128 + t]);
    }
}

// ------------- BN1 apply + relu in place (scale/shift computed inline) -------------
__global__ __launch_bounds__(256) void k_bn_apply_pad(bf16* __restrict__ t,
                                                      const float* __restrict__ sums,
                                                      const float* __restrict__ g,
                                                      const float* __restrict__ bb){
    __shared__ float ssc[256];
    int tt = threadIdx.x;
    if (tt < 128){
        float mean = sums[tt] / (float)NPIX;
        float var  = sums[128 + tt] / (float)NPIX - mean * mean;
        float scale = g[tt] * rsqrtf(var + EPS);
        ssc[tt]       = scale;
        ssc[128 + tt] = bb[tt] - mean * scale;
    }
    __syncthreads();
    int i = blockIdx.x * 256 + tt;
    if (i >= NPIX * CO) return;
    int c = i & 127;
    int pix = i >> 7;
    int xw = pix & 127, yh = (pix >> 7) & 127, b = pix >> 14;
    size_t a = (((size_t)b * WP + yh + 1) * WP + xw + 1) * CO + c;
    float v = b2f(t[a]) * ssc[c] + ssc[128 + c];
    t[a] = f2b(v > 0.f ? v : 0.f);
}

// ------------- offset conv: row-resident A + per-ky B, MFMA -------------
__global__ __launch_bounds__(256) void k_conv_off_mfma(const bf16* __restrict__ hp,
                                                       const bf16* __restrict__ wob,
                                                       const float* __restrict__ off_b,
                                                       bf16* __restrict__ offs){
    __shared__ unsigned short Ab[132 * 128];   // 33792 B
    __shared__ unsigned short Bb[32 * 384];    // 24576 B
    int t = threadIdx.x, l = t & 63, w = t >> 6;
    int y = blockIdx.x % H, b = blockIdx.x / H;
    int m = l & 15, quad = l >> 4;
    int wm = w & 1, wn = w >> 1;

    f32x4 acc[4];
#pragma unroll
    for (int i = 0; i < 4; i++) acc[i] = f32x4{0.f, 0.f, 0.f, 0.f};

    const size_t rowStrideH = (size_t)WP * CO;
    for (int ky = 0; ky < 3; ky++){
        const bf16* Arow = hp + ((size_t)(b * WP) + y + ky) * rowStrideH;
        __syncthreads();
        for (int i = w; i < 33; i += 4){       // A: full hp row once per ky
            int G  = i * 64 + l;
            int px = G >> 4, ol = G & 15;
            int osrc = ol ^ (px & 7);
            async_copy16(Arow + (size_t)px * CO + osrc * 8, &Ab[i * 512]);
        }
        for (int i = w; i < 24; i += 4){       // B: 32oc x 384k for this ky
            int g  = i * 64 + l;
            int kx = g >> 9, oc = (g >> 4) & 31, ol = g & 15;
            int osrc = ol ^ (oc & 7);
            async_copy16(wob + (size_t)oc * KD + ky * 384 + kx * 128 + osrc * 8,
                         &Bb[i * 512]);
        }
        __syncthreads();
        const bf16x8* ap = (const bf16x8*)Ab;
        const bf16x8* bp = (const bf16x8*)Bb;
        for (int kx = 0; kx < 3; kx++){
#pragma unroll
            for (int s = 0; s < 4; s++){
                int oc = wn * 16 + m;
                bf16x8 bfr = bp[kx * 512 + oc * 16 + ((s * 4 + quad) ^ (oc & 7))];
#pragma unroll
                for (int mi = 0; mi < 4; mi++){
                    int pxk = wm * 64 + mi * 16 + m + kx;
                    bf16x8 af = ap[pxk * 16 + ((s * 4 + quad) ^ (pxk & 7))];
                    acc[mi] = __builtin_amdgcn_mfma_f32_16x16x32_bf16(af, bfr, acc[mi], 0, 0, 0);
                }
            }
        }
    }
    int oc = wn * 16 + m;
    if (oc < 18){
        float bias = off_b[oc];
        int rowpix = b * HW + y * W;
#pragma unroll
        for (int mi = 0; mi < 4; mi++){
            int p0 = wm * 64 + mi * 16 + quad * 4;
#pragma unroll
            for (int r = 0; r < 4; r++)
                offs[(size_t)(rowpix + p0 + r) * 18 + oc] = f2b(acc[mi][r] + bias);
        }
    }
}

// ------------- deform: A-gen in LDS + MFMA GEMM + fused BN2 stats -------------
__global__ __launch_bounds__(256) void k_deform_mfma(const bf16* __restrict__ hp,
                                                     const bf16* __restrict__ offs,
                                                     const bf16* __restrict__ wdb,
                                                     const float* __restrict__ def_b,
                                                     bf16* __restrict__ y,
                                                     float* __restrict__ sums){
    __shared__ unsigned short Ab[128 * 64];
    __shared__ unsigned short Bb[128 * 64];
    __shared__ int2   sc_yx[9 * 128];
    __shared__ float4 sc_w[9 * 128];
    __shared__ float  ps[256];

    int t = threadIdx.x, l = t & 63, w = t >> 6;
    int yrow = blockIdx.x % H, b = blockIdx.x / H;
    int rowpix = b * HW + yrow * W;

    for (int idx = t; idx < 9 * 128; idx += 256){
        int kp = idx >> 7, px = idx & 127;
        float dy = b2f(offs[(size_t)(rowpix + px) * 18 + 2 * kp]);
        float dx = b2f(offs[(size_t)(rowpix + px) * 18 + 2 * kp + 1]);
        float py = yrow + (kp / 3 - 1) + dy;
        float pxx = px + (kp % 3 - 1) + dx;
        float fy = floorf(py), fx = floorf(pxx);
        float wy = py - fy, wx = pxx - fx;
        int y0 = (int)fy, x0 = (int)fx;
        bool vy0 = (y0 >= 0) && (y0 < H);
        bool vy1 = (y0 + 1 >= 0) && (y0 + 1 < H);
        bool vx0 = (x0 >= 0) && (x0 < W);
        bool vx1 = (x0 + 1 >= 0) && (x0 + 1 < W);
        int y0c = min(max(y0, 0), H - 1),     y1c = min(max(y0 + 1, 0), H - 1);
        int x0c = min(max(x0, 0), W - 1),     x1c = min(max(x0 + 1, 0), W - 1);
        sc_yx[idx] = make_int2(((y0c + 1) * WP) | (((y1c + 1) * WP) << 16),
                               (x0c + 1) | ((x1c + 1) << 16));
        sc_w[idx] = make_float4((1 - wy) * (1 - wx) * (float)(vy0 && vx0),
                                (1 - wy) * wx       * (float)(vy0 && vx1),
                                wy * (1 - wx)       * (float)(vy1 && vx0),
                                wy * wx             * (float)(vy1 && vx1));
    }
    __syncthreads();

    int pr = l >> 3, koct = (l & 7) ^ pr;
    int m = l & 15, quad = l >> 4;
    int wm = w & 1, wn = w >> 1;
    int g = l >> 4, j = l & 15;

    f32x4 acc[4][4];
#pragma unroll
    for (int i = 0; i < 4; i++)
#pragma unroll
        for (int jj = 0; jj < 4; jj++) acc[i][jj] = f32x4{0.f, 0.f, 0.f, 0.f};

    const bf16* hpb = hp + (size_t)b * WP * WP * CO;

    for (int kc = 0; kc < 18; kc++){
        int kp = kc >> 1, ch = (kc & 1) * 64;
        __syncthreads();
        int kg = kp * 128 + ch;
#pragma unroll
        for (int i = 0; i < 4; i++){
            int oc = w * 32 + i * 8 + pr;
            async_copy16(wdb + (size_t)oc * KD + kg + koct * 8,
                         &Bb[(w * 32 + i * 8) * 64]);
        }
        int cb = ch + j * 4;
#pragma unroll
        for (int p = 0; p < 8; p++){
            int px = w * 32 + g * 8 + p;
            int idx = kp * 128 + px;
            int2 yx = sc_yx[idx];
            float4 w4 = sc_w[idx];
            int r0 = yx.x & 0xffff, r1 = ((unsigned)yx.x) >> 16;
            int c0 = yx.y & 0xffff, c1 = ((unsigned)yx.y) >> 16;
            const bf16* base = hpb + cb;
            bf16x4 s00 = *(const bf16x4*)(base + (size_t)(r0 + c0) * CO);
            bf16x4 s01 = *(const bf16x4*)(base + (size_t)(r0 + c1) * CO);
            bf16x4 s10 = *(const bf16x4*)(base + (size_t)(r1 + c0) * CO);
            bf16x4 s11 = *(const bf16x4*)(base + (size_t)(r1 + c1) * CO);
            bf16x4 pv;
#pragma unroll
            for (int r = 0; r < 4; r++){
                float v = w4.x * (float)s00[r] + w4.y * (float)s01[r]
                        + w4.z * (float)s10[r] + w4.w * (float)s11[r];
                pv[r] = (__bf16)v;
            }
            int oct_sw = (j >> 1) ^ (px & 7);
            *(bf16x4*)&Ab[px * 64 + oct_sw * 8 + (j & 1) * 4] = pv;
        }
        __syncthreads();
        const bf16x8* ap = (const bf16x8*)Ab;
        const bf16x8* bp = (const bf16x8*)Bb;
#pragma unroll
        for (int ks = 0; ks < 2; ks++){
            bf16x8 af[4], bfr[4];
#pragma unroll
            for (int mi = 0; mi < 4; mi++){
                int px = wm * 64 + mi * 16 + m;
                af[mi] = ap[px * 8 + ((ks * 4 + quad) ^ (px & 7))];
            }
#pragma unroll
            for (int ni = 0; ni < 4; ni++){
                int oc = wn * 64 + ni * 16 + m;
                bfr[ni] = bp[oc * 8 + ((ks * 4 + quad) ^ (oc & 7))];
            }
#pragma unroll
            for (int mi = 0; mi < 4; mi++)
#pragma unroll
                for (int ni = 0; ni < 4; ni++)
                    acc[mi][ni] = __builtin_amdgcn_mfma_f32_16x16x32_bf16(
                        af[mi], bfr[ni], acc[mi][ni], 0, 0, 0);
        }
    }
#pragma unroll
    for (int mi = 0; mi < 4; mi++){
        int p0 = wm * 64 + mi * 16 + quad * 4;
#pragma unroll
        for (int ni = 0; ni < 4; ni++){
            int oc = wn * 64 + ni * 16 + m;
            float bias = def_b[oc];
#pragma unroll
            for (int r = 0; r < 4; r++)
                y[(size_t)(rowpix + p0 + r) * CO + oc] = f2b(acc[mi][ni][r] + bias);
        }
    }
    // fused BN2 stats (shfl quad-reduction)
    ps[t] = 0.f;
    __syncthreads();
#pragma unroll
    for (int ni = 0; ni < 4; ni++){
        int ch = wn * 64 + ni * 16 + m;
        float bias = def_b[ch];
        float s = 0.f, q = 0.f;
#pragma unroll
        for (int mi = 0; mi < 4; mi++)
#pragma unroll
            for (int r = 0; r < 4; r++){
                float v = acc[mi][ni][r] + bias;
                s += v; q += v * v;
            }
        s += __shfl_xor(s, 16); s += __shfl_xor(s, 32);
        q += __shfl_xor(q, 16); q += __shfl_xor(q, 32);
        if (quad == 0){
            atomicAdd(&ps[ch], s);
            atomicAdd(&ps[128 + ch], q);
        }
    }
    __syncthreads();
    if (t < 128){
        atomicAdd(&sums[t],       ps[t]);
        atomicAdd(&sums[128 + t], ps[128 + t]);
    }
}

// ------------- BN2 apply + relu + NHWC->NCHW (scale/shift inline) -------------
__global__ __launch_bounds__(256) void k_final(const bf16* __restrict__ yb,
                                               const float* __restrict__ sums,
                                               const float* __restrict__ g,
                                               const float* __restrict__ bb,
                                               float* __restrict__ out){
    __shared__ unsigned short tile[128 * 129];
    __shared__ float ssc[256];
    int t = threadIdx.x;
    if (t < 128){
        float mean = sums[t] / (float)NPIX;
        float var  = sums[128 + t] / (float)NPIX - mean * mean;
        float scale = g[t] * rsqrtf(var + EPS);
        ssc[t]       = scale;
        ssc[128 + t] = bb[t] - mean * scale;
    }
    int yrow = blockIdx.x % H, b = blockIdx.x / H;
    int rowbase = b * HW + yrow * W;
    const unsigned short* src = (const unsigned short*)yb;
    for (int it = 0; it < 64; it++){
        int idx = it * 256 + t;
        int c = idx & 127, px = idx >> 7;
        tile[px * 129 + c] = src[(size_t)(rowbase + px) * CO + c];
    }
    __syncthreads();
    for (int it = 0; it < 64; it++){
        int idx = it * 256 + t;
        int xw = idx & 127, o = idx >> 7;
        unsigned short u = tile[xw * 129 + o];
        float v = (float)(*(const __bf16*)&u);
        v = v * ssc[o] + ssc[128 + o];
        out[(((size_t)b * CO + o) * H + yrow) * W + xw] = v > 0.f ? v : 0.f;
    }
}

extern "C" void kernel_launch(void* const* d_in, const int* in_sizes, int n_in,
                              void* d_out, int out_size, void* d_ws, size_t ws_size,
                              hipStream_t stream){
    const float* x      = (const float*)d_in[0];
    const float* skip   = (const float*)d_in[1];
    const float* conv1w = (const float*)d_in[2];
    const float* bn1g   = (const float*)d_in[3];
    const float* bn1b   = (const float*)d_in[4];
    const float* offw   = (const float*)d_in[5];
    const float* offb   = (const float*)d_in[6];
    const float* defw   = (const float*)d_in[7];
    const float* defb   = (const float*)d_in[8];
    const float* bn2g   = (const float*)d_in[9];
    const float* bn2b   = (const float*)d_in[10];
    float* out = (float*)d_out;

    char* ws = (char*)d_ws;
    size_t off_bytes = 0;
    auto alloc = [&](size_t bytes) -> void* {
        void* p = ws + off_bytes;
        off_bytes += (bytes + 255) & ~(size_t)255;
        return p;
    };
    const size_t catp_elems = (size_t)NB * WP * WP * CCAT;
    const size_t hp_elems   = (size_t)NB * WP * WP * CO;
    bf16*  catp  = (bf16*) alloc(catp_elems * 2 + 2048);     // +tail pad for 2px overread
    bf16*  hp    = (bf16*) alloc(hp_elems * 2);              // 17.3 MB
    bf16*  offs  = (bf16*) alloc((size_t)NPIX * 18 * 2);
    bf16*  yb    = (bf16*) alloc((size_t)NPIX * CO * 2);
    bf16*  wbt   = (bf16*) alloc((size_t)CO * K1 * 2);
    bf16*  wob   = (bf16*) alloc((size_t)32 * KD * 2);
    bf16*  wdb   = (bf16*) alloc((size_t)CO * KD * 2);
    float* sums  = (float*)alloc(512 * 4);
    float* sums1 = sums;
    float* sums2 = sums + 256;

    k_prep<<<1024, 256, 0, stream>>>(sums, catp, hp);

    k_build_cat2<<<NB * H, 256, 0, stream>>>(x, skip, catp);

    const int ntr = CO * K1 + 32 * KD + CO * KD;
    k_tr_all<<<(ntr + 255) / 256, 256, 0, stream>>>(conv1w, offw, defw, wbt, wob, wdb);

    k_conv1_mfma<<<NB * H * 2, 256, 0, stream>>>(catp, wbt, hp, sums1);

    k_bn_apply_pad<<<(NPIX * CO + 255) / 256, 256, 0, stream>>>(hp, sums1, bn1g, bn1b);

    k_conv_off_mfma<<<NB * H, 256, 0, stream>>>(hp, wob, offb, offs);

    k_deform_mfma<<<NB * H, 256, 0, stream>>>(hp, offs, wdb, defb, yb, sums2);

    k_final<<<NB * H, 256, 0, stream>>>(yb, sums2, bn2g, bn2b, out);
}

// Round 3
// 358.944 us; speedup vs baseline: 1.0354x; 1.0354x over previous
//
#include <hip/hip_runtime.h>
#include <hip/hip_bf16.h>

typedef __hip_bfloat16 bf16;
typedef __bf16 bf16x8 __attribute__((ext_vector_type(8)));
typedef __bf16 bf16x4 __attribute__((ext_vector_type(4)));
typedef float  f32x4  __attribute__((ext_vector_type(4)));

constexpr int NB   = 4;
constexpr int H    = 128;
constexpr int W    = 128;
constexpr int HW   = H * W;
constexpr int NPIX = NB * HW;        // 65536
constexpr int CCAT = 384;
constexpr int CSKIP= 128;
constexpr int CIN  = 256;
constexpr int CO   = 128;
constexpr int HS   = 64;
constexpr int WP   = 130;            // padded H/W
constexpr int K1   = 3456;           // conv1 GEMM K
constexpr int KD   = 1152;           // deform/off GEMM K
constexpr int NBORD= 2 * WP + 2 * (WP - 2);   // 516 border px per image
constexpr float EPS = 1e-5f;

__device__ __forceinline__ float b2f(bf16 v){ return __bfloat162float(v); }
__device__ __forceinline__ bf16  f2b(float v){ return __float2bfloat16(v); }

__device__ __forceinline__ void async_copy16(const void* g, void* s){
    __builtin_amdgcn_global_load_lds((const __attribute__((address_space(1))) void*)g,
                                     (__attribute__((address_space(3))) void*)s, 16, 0, 0);
}

// map border index 0..515 -> (y,x) on the WPxWP frame
__device__ __forceinline__ void border_yx(int p, int& y, int& x){
    if (p < WP)             { y = 0;        x = p; }
    else if (p < 2 * WP)    { y = WP - 1;   x = p - WP; }
    else if (p < 2 * WP + (WP - 2)) { y = p - 2 * WP + 1;          x = 0; }
    else                    { y = p - (2 * WP + (WP - 2)) + 1;     x = WP - 1; }
}

// ------------- prep: zero stat buffers + padded borders -------------
__global__ void k_prep(float* __restrict__ sums, bf16* __restrict__ catp,
                       bf16* __restrict__ hp){
    int i = blockIdx.x * blockDim.x + threadIdx.x;
    int stride = gridDim.x * blockDim.x;
    for (int j = i; j < 512; j += stride) sums[j] = 0.f;
    const int nCat = NB * NBORD * CCAT;
    for (int j = i; j < nCat; j += stride){
        int c = j % CCAT, r = j / CCAT, p = r % NBORD, b = r / NBORD;
        int y, x; border_yx(p, y, x);
        catp[(((size_t)b * WP + y) * WP + x) * CCAT + c] = f2b(0.f);
    }
    const int nHp = NB * NBORD * CO;
    for (int j = i; j < nHp; j += stride){
        int c = j % CO, r = j / CO, p = r % NBORD, b = r / NBORD;
        int y, x; border_yx(p, y, x);
        hp[(((size_t)b * WP + y) * WP + x) * CO + c] = f2b(0.f);
    }
}

// ------------- build cat interior via LDS transpose -------------
__global__ __launch_bounds__(256) void k_build_cat2(const float* __restrict__ x,
                                                    const float* __restrict__ skip,
                                                    bf16* __restrict__ catp){
    constexpr int TS = 66;
    __shared__ bf16 tile[128 * TS];
    int t  = threadIdx.x;
    int y  = blockIdx.x % H, b = blockIdx.x / H;
    int xx = t & 127, cp = t >> 7;

    float cy = (y * 63.0f) / 127.0f;
    int   y0 = (int)cy;
    int   y1 = min(y0 + 1, HS - 1);
    float wy = cy - y0;
    float cxf = (xx * 63.0f) / 127.0f;
    int   x0 = (int)cxf;
    int   x1 = min(x0 + 1, HS - 1);
    float wx = cxf - x0;

    bf16* orow = catp + (((size_t)b * WP + y + 1) * WP + 1) * CCAT;

    for (int chunk = 0; chunk < 6; chunk++){
        int cbase = chunk * 64;
        if (chunk >= 1) __syncthreads();
        if (chunk < 2){
            const float* sb = skip + ((size_t)(b * CSKIP + cbase + cp * 32) * H + y) * W;
#pragma unroll
            for (int i = 0; i < 32; i++)
                tile[xx * TS + cp * 32 + i] = f2b(sb[(size_t)i * HW + xx]);
        } else {
            int icb = (chunk - 2) * 64 + cp * 32;
            const float* xr0 = x + ((size_t)(b * CIN + icb) * HS + y0) * HS;
            const float* xr1 = x + ((size_t)(b * CIN + icb) * HS + y1) * HS;
#pragma unroll
            for (int i = 0; i < 32; i++){
                const float* r0 = xr0 + (size_t)i * HS * HS;
                const float* r1 = xr1 + (size_t)i * HS * HS;
                float v0 = r0[x0] * (1 - wx) + r0[x1] * wx;
                float v1 = r1[x0] * (1 - wx) + r1[x1] * wx;
                tile[xx * TS + cp * 32 + i] = f2b(v0 * (1 - wy) + v1 * wy);
            }
        }
        __syncthreads();
        int cc2 = (t & 31) * 2;
        int px0 = t >> 5;
#pragma unroll
        for (int pp = 0; pp < 16; pp++){
            int px = pp * 8 + px0;
            unsigned int v = *(const unsigned int*)&tile[px * TS + cc2];
            *(unsigned int*)&orow[(size_t)px * CCAT + cbase + cc2] = v;
        }
    }
}

// ------------- all weight transposes in one kernel -------------
__global__ void k_tr_all(const float* __restrict__ w1, const float* __restrict__ wo,
                         const float* __restrict__ wd,
                         bf16* __restrict__ wt1, bf16* __restrict__ wto,
                         bf16* __restrict__ wtd){
    int i = blockIdx.x * blockDim.x + threadIdx.x;
    if (i < CO * K1){
        int k = i % K1, oc = i / K1;
        int ky = k / 1152, r = k % 1152, kx = r / 384, ic = r % 384;
        wt1[i] = f2b(w1[((oc * CCAT + ic) * 3 + ky) * 3 + kx]);
        return;
    }
    i -= CO * K1;
    if (i < 32 * KD){
        int kk = i % KD, o = i / KD;
        int ky = kk / 384, r = kk % 384, kx = r >> 7, ic = r & 127;
        wto[i] = (o < 18) ? f2b(wo[((o * CO + ic) * 3 + ky) * 3 + kx]) : f2b(0.f);
        return;
    }
    i -= 32 * KD;
    if (i < CO * KD){
        int kk = i % KD, o = i / KD;
        int kp = kk >> 7, c = kk & 127;
        wtd[i] = f2b(wd[(o * CO + c) * 9 + kp]);
    }
}

// ------------- conv1: fine-interleaved counted-vmcnt pipeline -------------
// 54 phases, one per K-step-64 (s64 in kx in ci in ky). Per phase:
//   gate(prev) done -> ds_read all 12 b128 operands -> lgkmcnt(0) -> bar1
//   -> stage B(p+2) into the buffer just freed (+A(g+1) at q==2)
//   -> setprio(1) 16 MFMA setprio(0) -> counted vmcnt gate -> bar2.
// B prefetch distance = 2 phases; A prefetch = ~4 phases (gated at q==4's
// vmcnt(4) which drains A + B(p+1)). Gates exact per FIFO trace:
//   steady vmcnt(4); q==2/3 (A in flight) vmcnt(9); p==52 vmcnt(0).
// Raw s_barrier (no vmcnt(0) drain); empty-asm fences pin memory ops.
__global__ __launch_bounds__(256) void k_conv1_mfma(const bf16* __restrict__ catp,
                                                    const bf16* __restrict__ wbt,
                                                    bf16* __restrict__ hp,
                                                    float* __restrict__ sums){
    __shared__ unsigned short Ab[2][68 * 128];   // 2 x 17408 B
    __shared__ unsigned short Bb[2][128 * 64];   // 2 x 16384 B
    __shared__ float ps[256];
    int t = threadIdx.x;
    int l = t & 63, w = t >> 6;
    int half = blockIdx.x & 1;
    int y = (blockIdx.x >> 1) % H, b = blockIdx.x / (2 * H);
    int px0 = half * 64;

    int pr   = l >> 3;
    int koct = (l & 7) ^ pr;
    int m    = l & 15, quad = l >> 4;
    int wm   = w & 1,  wn   = w >> 1;

    f32x4 acc[2][4];
#pragma unroll
    for (int i = 0; i < 2; i++)
#pragma unroll
        for (int j = 0; j < 4; j++) acc[i][j] = f32x4{0.f, 0.f, 0.f, 0.f};

    const size_t rowStride = (size_t)WP * CCAT;

    // ---- prologue: A(0) then B(0) then B(1) (FIFO order = gate math) ----
    {
        const bf16* Arow0 = catp + ((size_t)(b * WP) + y) * rowStride + (size_t)px0 * CCAT;
#pragma unroll
        for (int k = 0; k < 5; k++){
            int i = min(w + k * 4, 16);
            int G = i * 64 + l;
            int px = G >> 4, ol = G & 15;
            int osrc = ol ^ (px & 7);
            async_copy16(Arow0 + (size_t)px * CCAT + osrc * 8, &Ab[0][i * 512]);
        }
#pragma unroll
        for (int i = 0; i < 4; i++){
            int ocg = w * 32 + i * 8;
            async_copy16(wbt + (size_t)(ocg + pr) * K1 + koct * 8, &Bb[0][ocg * 64]);
        }
#pragma unroll
        for (int i = 0; i < 4; i++){
            int ocg = w * 32 + i * 8;
            async_copy16(wbt + (size_t)(ocg + pr) * K1 + 64 + koct * 8, &Bb[1][ocg * 64]);
        }
        asm volatile("s_waitcnt vmcnt(4)" ::: "memory");   // A(0)+B(0) landed
        asm volatile("" ::: "memory");
        __builtin_amdgcn_s_barrier();
        asm volatile("" ::: "memory");
    }

#pragma unroll 1
    for (int p = 0; p < 54; p++){
        int gp = p / 6, q = p - gp * 6;
        int kx = q >> 1, s64 = q & 1;

        // ---- ds_read this phase's operands (gated by prev phase) ----
        const bf16x8* ap = (const bf16x8*)&Ab[gp & 1][0];
        const bf16x8* bp = (const bf16x8*)&Bb[p & 1][0];
        bf16x8 af[2][2], bfr[2][4];
#pragma unroll
        for (int ks = 0; ks < 2; ks++){
            int s = s64 * 2 + ks;
#pragma unroll
            for (int mi = 0; mi < 2; mi++){
                int pxk = wm * 32 + mi * 16 + m + kx;
                af[ks][mi] = ap[pxk * 16 + ((s * 4 + quad) ^ (pxk & 7))];
            }
#pragma unroll
            for (int ni = 0; ni < 4; ni++){
                int oc = wn * 64 + ni * 16 + m;
                bfr[ks][ni] = bp[oc * 8 + ((ks * 4 + quad) ^ (oc & 7))];
            }
        }
        asm volatile("s_waitcnt lgkmcnt(0)" ::: "memory"); // own reads done pre-bar1
        asm volatile("" ::: "memory");
        __builtin_amdgcn_s_barrier();                      // bar1: all reads done
        asm volatile("" ::: "memory");

        // ---- stage B(p+2) into the buffer just freed ----
        if (p < 52){
            int T = p + 2;
            int gT = T / 6, jT = T - gT * 6;
            int kgn = (gT / 3) * 1152 + (jT >> 1) * 384 + (gT % 3) * 128 + (jT & 1) * 64;
#pragma unroll
            for (int i = 0; i < 4; i++){
                int ocg = w * 32 + i * 8;
                async_copy16(wbt + (size_t)(ocg + pr) * K1 + kgn + koct * 8,
                             &Bb[T & 1][ocg * 64]);
            }
        }
        // ---- stage A(g+1) once per group ----
        if (q == 2 && gp < 8){
            int gn = gp + 1;
            int kyn = gn / 3, cin = gn - kyn * 3;
            const bf16* Arow2 = catp + ((size_t)(b * WP) + y + kyn) * rowStride
                              + (size_t)px0 * CCAT + cin * 128;
#pragma unroll
            for (int k = 0; k < 5; k++){
                int i = min(w + k * 4, 16);
                int G = i * 64 + l;
                int px = G >> 4, ol = G & 15;
                int osrc = ol ^ (px & 7);
                async_copy16(Arow2 + (size_t)px * CCAT + osrc * 8, &Ab[gn & 1][i * 512]);
            }
        }

        // ---- MFMA (staging latency hides under this) ----
        __builtin_amdgcn_s_setprio(1);
#pragma unroll
        for (int ks = 0; ks < 2; ks++)
#pragma unroll
            for (int mi = 0; mi < 2; mi++)
#pragma unroll
                for (int ni = 0; ni < 4; ni++)
                    acc[mi][ni] = __builtin_amdgcn_mfma_f32_16x16x32_bf16(
                        af[ks][mi], bfr[ks][ni], acc[mi][ni], 0, 0, 0);
        __builtin_amdgcn_s_setprio(0);

        // ---- counted gate for B(p+1) (+A drain at q==4), then bar2 ----
        if (p < 53){
            if (p == 52)                     asm volatile("s_waitcnt vmcnt(0)" ::: "memory");
            else if ((q == 2 || q == 3) && gp < 8)
                                             asm volatile("s_waitcnt vmcnt(9)" ::: "memory");
            else                             asm volatile("s_waitcnt vmcnt(4)" ::: "memory");
            asm volatile("" ::: "memory");
            __builtin_amdgcn_s_barrier();
            asm volatile("" ::: "memory");
        }
    }

    size_t obase = (((size_t)b * WP + y + 1) * WP + 1 + px0) * CO;
#pragma unroll
    for (int mi = 0; mi < 2; mi++){
        int p0 = wm * 32 + mi * 16 + quad * 4;
#pragma unroll
        for (int ni = 0; ni < 4; ni++){
            int oc = wn * 64 + ni * 16 + m;
#pragma unroll
            for (int r = 0; r < 4; r++)
                hp[obase + (size_t)(p0 + r) * CO + oc] = f2b(acc[mi][ni][r]);
        }
    }
    // fused BN1 stats (shfl quad-reduce -> LDS -> one global atomic per ch)
    ps[t] = 0.f;
    __syncthreads();
#pragma unroll
    for (int ni = 0; ni < 4; ni++){
        int ch = wn * 64 + ni * 16 + m;
        float s = 0.f, q2 = 0.f;
#pragma unroll
        for (int mi = 0; mi < 2; mi++)
#pragma unroll
            for (int r = 0; r < 4; r++){
                float v = acc[mi][ni][r];
                s += v; q2 += v * v;
            }
        s += __shfl_xor(s, 16); s += __shfl_xor(s, 32);
        q2 += __shfl_xor(q2, 16); q2 += __shfl_xor(q2, 32);
        if (quad == 0){
            atomicAdd(&ps[ch], s);
            atomicAdd(&ps[128 + ch], q2);
        }
    }
    __syncthreads();
    if (t < 128){
        atomicAdd(&sums[t],       ps[t]);
        atomicAdd(&sums[128 + t], ps[128 + t]);
    }
}

// ------------- BN1 apply + relu in place (scale/shift computed inline) -------------
__global__ __launch_bounds__(256) void k_bn_apply_pad(bf16* __restrict__ t,
                                                      const float* __restrict__ sums,
                                                      const float* __restrict__ g,
                                                      const float* __restrict__ bb){
    __shared__ float ssc[256];
    int tt = threadIdx.x;
    if (tt < 128){
        float mean = sums[tt] / (float)NPIX;
        float var  = sums[128 + tt] / (float)NPIX - mean * mean;
        float scale = g[tt] * rsqrtf(var + EPS);
        ssc[tt]       = scale;
        ssc[128 + tt] = bb[tt] - mean * scale;
    }
    __syncthreads();
    int i = blockIdx.x * 256 + tt;
    if (i >= NPIX * CO) return;
    int c = i & 127;
    int pix = i >> 7;
    int xw = pix & 127, yh = (pix >> 7) & 127, b = pix >> 14;
    size_t a = (((size_t)b * WP + yh + 1) * WP + xw + 1) * CO + c;
    float v = b2f(t[a]) * ssc[c] + ssc[128 + c];
    t[a] = f2b(v > 0.f ? v : 0.f);
}

// ------------- offset conv: row-resident A + per-ky B, MFMA -------------
__global__ __launch_bounds__(256) void k_conv_off_mfma(const bf16* __restrict__ hp,
                                                       const bf16* __restrict__ wob,
                                                       const float* __restrict__ off_b,
                                                       bf16* __restrict__ offs){
    __shared__ unsigned short Ab[132 * 128];   // 33792 B
    __shared__ unsigned short Bb[32 * 384];    // 24576 B
    int t = threadIdx.x, l = t & 63, w = t >> 6;
    int y = blockIdx.x % H, b = blockIdx.x / H;
    int m = l & 15, quad = l >> 4;
    int wm = w & 1, wn = w >> 1;

    f32x4 acc[4];
#pragma unroll
    for (int i = 0; i < 4; i++) acc[i] = f32x4{0.f, 0.f, 0.f, 0.f};

    const size_t rowStrideH = (size_t)WP * CO;
    for (int ky = 0; ky < 3; ky++){
        const bf16* Arow = hp + ((size_t)(b * WP) + y + ky) * rowStrideH;
        __syncthreads();
        for (int i = w; i < 33; i += 4){       // A: full hp row once per ky
            int G  = i * 64 + l;
            int px = G >> 4, ol = G & 15;
            int osrc = ol ^ (px & 7);
            async_copy16(Arow + (size_t)px * CO + osrc * 8, &Ab[i * 512]);
        }
        for (int i = w; i < 24; i += 4){       // B: 32oc x 384k for this ky
            int g  = i * 64 + l;
            int kx = g >> 9, oc = (g >> 4) & 31, ol = g & 15;
            int osrc = ol ^ (oc & 7);
            async_copy16(wob + (size_t)oc * KD + ky * 384 + kx * 128 + osrc * 8,
                         &Bb[i * 512]);
        }
        __syncthreads();
        const bf16x8* ap = (const bf16x8*)Ab;
        const bf16x8* bp = (const bf16x8*)Bb;
        for (int kx = 0; kx < 3; kx++){
#pragma unroll
            for (int s = 0; s < 4; s++){
                int oc = wn * 16 + m;
                bf16x8 bfr = bp[kx * 512 + oc * 16 + ((s * 4 + quad) ^ (oc & 7))];
#pragma unroll
                for (int mi = 0; mi < 4; mi++){
                    int pxk = wm * 64 + mi * 16 + m + kx;
                    bf16x8 af = ap[pxk * 16 + ((s * 4 + quad) ^ (pxk & 7))];
                    acc[mi] = __builtin_amdgcn_mfma_f32_16x16x32_bf16(af, bfr, acc[mi], 0, 0, 0);
                }
            }
        }
    }
    int oc = wn * 16 + m;
    if (oc < 18){
        float bias = off_b[oc];
        int rowpix = b * HW + y * W;
#pragma unroll
        for (int mi = 0; mi < 4; mi++){
            int p0 = wm * 64 + mi * 16 + quad * 4;
#pragma unroll
            for (int r = 0; r < 4; r++)
                offs[(size_t)(rowpix + p0 + r) * 18 + oc] = f2b(acc[mi][r] + bias);
        }
    }
}

// ------------- deform: A-gen in LDS + MFMA GEMM + fused BN2 stats -------------
__global__ __launch_bounds__(256) void k_deform_mfma(const bf16* __restrict__ hp,
                                                     const bf16* __restrict__ offs,
                                                     const bf16* __restrict__ wdb,
                                                     const float* __restrict__ def_b,
                                                     bf16* __restrict__ y,
                                                     float* __restrict__ sums){
    __shared__ unsigned short Ab[128 * 64];
    __shared__ unsigned short Bb[128 * 64];
    __shared__ int2   sc_yx[9 * 128];
    __shared__ float4 sc_w[9 * 128];
    __shared__ float  ps[256];

    int t = threadIdx.x, l = t & 63, w = t >> 6;
    int yrow = blockIdx.x % H, b = blockIdx.x / H;
    int rowpix = b * HW + yrow * W;

    for (int idx = t; idx < 9 * 128; idx += 256){
        int kp = idx >> 7, px = idx & 127;
        float dy = b2f(offs[(size_t)(rowpix + px) * 18 + 2 * kp]);
        float dx = b2f(offs[(size_t)(rowpix + px) * 18 + 2 * kp + 1]);
        float py = yrow + (kp / 3 - 1) + dy;
        float pxx = px + (kp % 3 - 1) + dx;
        float fy = floorf(py), fx = floorf(pxx);
        float wy = py - fy, wx = pxx - fx;
        int y0 = (int)fy, x0 = (int)fx;
        bool vy0 = (y0 >= 0) && (y0 < H);
        bool vy1 = (y0 + 1 >= 0) && (y0 + 1 < H);
        bool vx0 = (x0 >= 0) && (x0 < W);
        bool vx1 = (x0 + 1 >= 0) && (x0 + 1 < W);
        int y0c = min(max(y0, 0), H - 1),     y1c = min(max(y0 + 1, 0), H - 1);
        int x0c = min(max(x0, 0), W - 1),     x1c = min(max(x0 + 1, 0), W - 1);
        sc_yx[idx] = make_int2(((y0c + 1) * WP) | (((y1c + 1) * WP) << 16),
                               (x0c + 1) | ((x1c + 1) << 16));
        sc_w[idx] = make_float4((1 - wy) * (1 - wx) * (float)(vy0 && vx0),
                                (1 - wy) * wx       * (float)(vy0 && vx1),
                                wy * (1 - wx)       * (float)(vy1 && vx0),
                                wy * wx             * (float)(vy1 && vx1));
    }
    __syncthreads();

    int pr = l >> 3, koct = (l & 7) ^ pr;
    int m = l & 15, quad = l >> 4;
    int wm = w & 1, wn = w >> 1;
    int g = l >> 4, j = l & 15;

    f32x4 acc[4][4];
#pragma unroll
    for (int i = 0; i < 4; i++)
#pragma unroll
        for (int jj = 0; jj < 4; jj++) acc[i][jj] = f32x4{0.f, 0.f, 0.f, 0.f};

    const bf16* hpb = hp + (size_t)b * WP * WP * CO;

    for (int kc = 0; kc < 18; kc++){
        int kp = kc >> 1, ch = (kc & 1) * 64;
        __syncthreads();
        int kg = kp * 128 + ch;
#pragma unroll
        for (int i = 0; i < 4; i++){
            int oc = w * 32 + i * 8 + pr;
            async_copy16(wdb + (size_t)oc * KD + kg + koct * 8,
                         &Bb[(w * 32 + i * 8) * 64]);
        }
        int cb = ch + j * 4;
#pragma unroll
        for (int p = 0; p < 8; p++){
            int px = w * 32 + g * 8 + p;
            int idx = kp * 128 + px;
            int2 yx = sc_yx[idx];
            float4 w4 = sc_w[idx];
            int r0 = yx.x & 0xffff, r1 = ((unsigned)yx.x) >> 16;
            int c0 = yx.y & 0xffff, c1 = ((unsigned)yx.y) >> 16;
            const bf16* base = hpb + cb;
            bf16x4 s00 = *(const bf16x4*)(base + (size_t)(r0 + c0) * CO);
            bf16x4 s01 = *(const bf16x4*)(base + (size_t)(r0 + c1) * CO);
            bf16x4 s10 = *(const bf16x4*)(base + (size_t)(r1 + c0) * CO);
            bf16x4 s11 = *(const bf16x4*)(base + (size_t)(r1 + c1) * CO);
            bf16x4 pv;
#pragma unroll
            for (int r = 0; r < 4; r++){
                float v = w4.x * (float)s00[r] + w4.y * (float)s01[r]
                        + w4.z * (float)s10[r] + w4.w * (float)s11[r];
                pv[r] = (__bf16)v;
            }
            int oct_sw = (j >> 1) ^ (px & 7);
            *(bf16x4*)&Ab[px * 64 + oct_sw * 8 + (j & 1) * 4] = pv;
        }
        __syncthreads();
        const bf16x8* ap = (const bf16x8*)Ab;
        const bf16x8* bp = (const bf16x8*)Bb;
#pragma unroll
        for (int ks = 0; ks < 2; ks++){
            bf16x8 af[4], bfr[4];
#pragma unroll
            for (int mi = 0; mi < 4; mi++){
                int px = wm * 64 + mi * 16 + m;
                af[mi] = ap[px * 8 + ((ks * 4 + quad) ^ (px & 7))];
            }
#pragma unroll
            for (int ni = 0; ni < 4; ni++){
                int oc = wn * 64 + ni * 16 + m;
                bfr[ni] = bp[oc * 8 + ((ks * 4 + quad) ^ (oc & 7))];
            }
#pragma unroll
            for (int mi = 0; mi < 4; mi++)
#pragma unroll
                for (int ni = 0; ni < 4; ni++)
                    acc[mi][ni] = __builtin_amdgcn_mfma_f32_16x16x32_bf16(
                        af[mi], bfr[ni], acc[mi][ni], 0, 0, 0);
        }
    }
#pragma unroll
    for (int mi = 0; mi < 4; mi++){
        int p0 = wm * 64 + mi * 16 + quad * 4;
#pragma unroll
        for (int ni = 0; ni < 4; ni++){
            int oc = wn * 64 + ni * 16 + m;
            float bias = def_b[oc];
#pragma unroll
            for (int r = 0; r < 4; r++)
                y[(size_t)(rowpix + p0 + r) * CO + oc] = f2b(acc[mi][ni][r] + bias);
        }
    }
    // fused BN2 stats (shfl quad-reduction)
    ps[t] = 0.f;
    __syncthreads();
#pragma unroll
    for (int ni = 0; ni < 4; ni++){
        int ch = wn * 64 + ni * 16 + m;
        float bias = def_b[ch];
        float s = 0.f, q = 0.f;
#pragma unroll
        for (int mi = 0; mi < 4; mi++)
#pragma unroll
            for (int r = 0; r < 4; r++){
                float v = acc[mi][ni][r] + bias;
                s += v; q += v * v;
            }
        s += __shfl_xor(s, 16); s += __shfl_xor(s, 32);
        q += __shfl_xor(q, 16); q += __shfl_xor(q, 32);
        if (quad == 0){
            atomicAdd(&ps[ch], s);
            atomicAdd(&ps[128 + ch], q);
        }
    }
    __syncthreads();
    if (t < 128){
        atomicAdd(&sums[t],       ps[t]);
        atomicAdd(&sums[128 + t], ps[128 + t]);
    }
}

// ------------- BN2 apply + relu + NHWC->NCHW (scale/shift inline) -------------
__global__ __launch_bounds__(256) void k_final(const bf16* __restrict__ yb,
                                               const float* __restrict__ sums,
                                               const float* __restrict__ g,
                                               const float* __restrict__ bb,
                                               float* __restrict__ out){
    __shared__ unsigned short tile[128 * 129];
    __shared__ float ssc[256];
    int t = threadIdx.x;
    if (t < 128){
        float mean = sums[t] / (float)NPIX;
        float var  = sums[128 + t] / (float)NPIX - mean * mean;
        float scale = g[t] * rsqrtf(var + EPS);
        ssc[t]       = scale;
        ssc[128 + t] = bb[t] - mean * scale;
    }
    int yrow = blockIdx.x % H, b = blockIdx.x / H;
    int rowbase = b * HW + yrow * W;
    const unsigned short* src = (const unsigned short*)yb;
    for (int it = 0; it < 64; it++){
        int idx = it * 256 + t;
        int c = idx & 127, px = idx >> 7;
        tile[px * 129 + c] = src[(size_t)(rowbase + px) * CO + c];
    }
    __syncthreads();
    for (int it = 0; it < 64; it++){
        int idx = it * 256 + t;
        int xw = idx & 127, o = idx >> 7;
        unsigned short u = tile[xw * 129 + o];
        float v = (float)(*(const __bf16*)&u);
        v = v * ssc[o] + ssc[128 + o];
        out[(((size_t)b * CO + o) * H + yrow) * W + xw] = v > 0.f ? v : 0.f;
    }
}

extern "C" void kernel_launch(void* const* d_in, const int* in_sizes, int n_in,
                              void* d_out, int out_size, void* d_ws, size_t ws_size,
                              hipStream_t stream){
    const float* x      = (const float*)d_in[0];
    const float* skip   = (const float*)d_in[1];
    const float* conv1w = (const float*)d_in[2];
    const float* bn1g   = (const float*)d_in[3];
    const float* bn1b   = (const float*)d_in[4];
    const float* offw   = (const float*)d_in[5];
    const float* offb   = (const float*)d_in[6];
    const float* defw   = (const float*)d_in[7];
    const float* defb   = (const float*)d_in[8];
    const float* bn2g   = (const float*)d_in[9];
    const float* bn2b   = (const float*)d_in[10];
    float* out = (float*)d_out;

    char* ws = (char*)d_ws;
    size_t off_bytes = 0;
    auto alloc = [&](size_t bytes) -> void* {
        void* p = ws + off_bytes;
        off_bytes += (bytes + 255) & ~(size_t)255;
        return p;
    };
    const size_t catp_elems = (size_t)NB * WP * WP * CCAT;
    const size_t hp_elems   = (size_t)NB * WP * WP * CO;
    bf16*  catp  = (bf16*) alloc(catp_elems * 2 + 2048);     // +tail pad for 2px overread
    bf16*  hp    = (bf16*) alloc(hp_elems * 2);              // 17.3 MB
    bf16*  offs  = (bf16*) alloc((size_t)NPIX * 18 * 2);
    bf16*  yb    = (bf16*) alloc((size_t)NPIX * CO * 2);
    bf16*  wbt   = (bf16*) alloc((size_t)CO * K1 * 2);
    bf16*  wob   = (bf16*) alloc((size_t)32 * KD * 2);
    bf16*  wdb   = (bf16*) alloc((size_t)CO * KD * 2);
    float* sums  = (float*)alloc(512 * 4);
    float* sums1 = sums;
    float* sums2 = sums + 256;

    k_prep<<<1024, 256, 0, stream>>>(sums, catp, hp);

    k_build_cat2<<<NB * H, 256, 0, stream>>>(x, skip, catp);

    const int ntr = CO * K1 + 32 * KD + CO * KD;
    k_tr_all<<<(ntr + 255) / 256, 256, 0, stream>>>(conv1w, offw, defw, wbt, wob, wdb);

    k_conv1_mfma<<<NB * H * 2, 256, 0, stream>>>(catp, wbt, hp, sums1);

    k_bn_apply_pad<<<(NPIX * CO + 255) / 256, 256, 0, stream>>>(hp, sums1, bn1g, bn1b);

    k_conv_off_mfma<<<NB * H, 256, 0, stream>>>(hp, wob, offb, offs);

    k_deform_mfma<<<NB * H, 256, 0, stream>>>(hp, offs, wdb, defb, yb, sums2);

    k_final<<<NB * H, 256, 0, stream>>>(yb, sums2, bn2g, bn2b, out);
}

// Round 4
// 333.868 us; speedup vs baseline: 1.1132x; 1.0751x over previous
//
#include <hip/hip_runtime.h>
#include <hip/hip_bf16.h>

typedef __hip_bfloat16 bf16;
typedef __bf16 bf16x8 __attribute__((ext_vector_type(8)));
typedef __bf16 bf16x4 __attribute__((ext_vector_type(4)));
typedef float  f32x4  __attribute__((ext_vector_type(4)));

constexpr int NB   = 4;
constexpr int H    = 128;
constexpr int W    = 128;
constexpr int HW   = H * W;
constexpr int NPIX = NB * HW;        // 65536
constexpr int CCAT = 384;
constexpr int CSKIP= 128;
constexpr int CIN  = 256;
constexpr int CO   = 128;
constexpr int HS   = 64;
constexpr int WP   = 130;            // padded H/W
constexpr int K1   = 3456;           // conv1 GEMM K
constexpr int KD   = 1152;           // deform/off GEMM K
constexpr int NBORD= 2 * WP + 2 * (WP - 2);   // 516 border px per image
constexpr float EPS = 1e-5f;

__device__ __forceinline__ float b2f(bf16 v){ return __bfloat162float(v); }
__device__ __forceinline__ bf16  f2b(float v){ return __float2bfloat16(v); }

__device__ __forceinline__ void async_copy16(const void* g, void* s){
    __builtin_amdgcn_global_load_lds((const __attribute__((address_space(1))) void*)g,
                                     (__attribute__((address_space(3))) void*)s, 16, 0, 0);
}

// map border index 0..515 -> (y,x) on the WPxWP frame
__device__ __forceinline__ void border_yx(int p, int& y, int& x){
    if (p < WP)             { y = 0;        x = p; }
    else if (p < 2 * WP)    { y = WP - 1;   x = p - WP; }
    else if (p < 2 * WP + (WP - 2)) { y = p - 2 * WP + 1;          x = 0; }
    else                    { y = p - (2 * WP + (WP - 2)) + 1;     x = WP - 1; }
}

// ------------- prep: zero stat buffers + padded borders -------------
__global__ void k_prep(float* __restrict__ sums, bf16* __restrict__ catp,
                       bf16* __restrict__ hp){
    int i = blockIdx.x * blockDim.x + threadIdx.x;
    int stride = gridDim.x * blockDim.x;
    for (int j = i; j < 512; j += stride) sums[j] = 0.f;
    const int nCat = NB * NBORD * CCAT;
    for (int j = i; j < nCat; j += stride){
        int c = j % CCAT, r = j / CCAT, p = r % NBORD, b = r / NBORD;
        int y, x; border_yx(p, y, x);
        catp[(((size_t)b * WP + y) * WP + x) * CCAT + c] = f2b(0.f);
    }
    const int nHp = NB * NBORD * CO;
    for (int j = i; j < nHp; j += stride){
        int c = j % CO, r = j / CO, p = r % NBORD, b = r / NBORD;
        int y, x; border_yx(p, y, x);
        hp[(((size_t)b * WP + y) * WP + x) * CO + c] = f2b(0.f);
    }
}

// ------------- build cat interior via LDS transpose -------------
__global__ __launch_bounds__(256) void k_build_cat2(const float* __restrict__ x,
                                                    const float* __restrict__ skip,
                                                    bf16* __restrict__ catp){
    constexpr int TS = 66;
    __shared__ bf16 tile[128 * TS];
    int t  = threadIdx.x;
    int y  = blockIdx.x % H, b = blockIdx.x / H;
    int xx = t & 127, cp = t >> 7;

    float cy = (y * 63.0f) / 127.0f;
    int   y0 = (int)cy;
    int   y1 = min(y0 + 1, HS - 1);
    float wy = cy - y0;
    float cxf = (xx * 63.0f) / 127.0f;
    int   x0 = (int)cxf;
    int   x1 = min(x0 + 1, HS - 1);
    float wx = cxf - x0;

    bf16* orow = catp + (((size_t)b * WP + y + 1) * WP + 1) * CCAT;

    for (int chunk = 0; chunk < 6; chunk++){
        int cbase = chunk * 64;
        if (chunk >= 1) __syncthreads();
        if (chunk < 2){
            const float* sb = skip + ((size_t)(b * CSKIP + cbase + cp * 32) * H + y) * W;
#pragma unroll
            for (int i = 0; i < 32; i++)
                tile[xx * TS + cp * 32 + i] = f2b(sb[(size_t)i * HW + xx]);
        } else {
            int icb = (chunk - 2) * 64 + cp * 32;
            const float* xr0 = x + ((size_t)(b * CIN + icb) * HS + y0) * HS;
            const float* xr1 = x + ((size_t)(b * CIN + icb) * HS + y1) * HS;
#pragma unroll
            for (int i = 0; i < 32; i++){
                const float* r0 = xr0 + (size_t)i * HS * HS;
                const float* r1 = xr1 + (size_t)i * HS * HS;
                float v0 = r0[x0] * (1 - wx) + r0[x1] * wx;
                float v1 = r1[x0] * (1 - wx) + r1[x1] * wx;
                tile[xx * TS + cp * 32 + i] = f2b(v0 * (1 - wy) + v1 * wy);
            }
        }
        __syncthreads();
        int cc2 = (t & 31) * 2;
        int px0 = t >> 5;
#pragma unroll
        for (int pp = 0; pp < 16; pp++){
            int px = pp * 8 + px0;
            unsigned int v = *(const unsigned int*)&tile[px * TS + cc2];
            *(unsigned int*)&orow[(size_t)px * CCAT + cbase + cc2] = v;
        }
    }
}

// ------------- all weight transposes in one kernel -------------
// conv1 weights emitted FRAGMENT-MAJOR: for phase p (54 = ky,ci,kx,s64),
// ks (2), oc-block nb (8), lane l (64): byte addr p*16384+ks*8192+nb*1024+l*16
// holds the 8 bf16 of lane l's MFMA B-fragment: oc=nb*16+(l&15),
// ic = ci*128+s64*64+ks*32+(l>>4)*8+e. Lets conv1 read B straight to VGPRs
// as coalesced 16B/lane loads (no LDS round-trip).
__global__ void k_tr_all(const float* __restrict__ w1, const float* __restrict__ wo,
                         const float* __restrict__ wd,
                         bf16* __restrict__ wt1, bf16* __restrict__ wto,
                         bf16* __restrict__ wtd){
    int i = blockIdx.x * blockDim.x + threadIdx.x;
    if (i < CO * K1){
        int e  = i & 7;
        int l  = (i >> 3) & 63;
        int nb = (i >> 9) & 7;
        int ks = (i >> 12) & 1;
        int p  = i >> 13;                 // 0..53
        int gp = p / 6, q = p - gp * 6;
        int ky = gp / 3, ci = gp - ky * 3;
        int kx = q >> 1, s64 = q & 1;
        int oc = nb * 16 + (l & 15);
        int ic = ci * 128 + s64 * 64 + ks * 32 + (l >> 4) * 8 + e;
        wt1[i] = f2b(w1[((oc * CCAT + ic) * 3 + ky) * 3 + kx]);
        return;
    }
    i -= CO * K1;
    if (i < 32 * KD){
        int kk = i % KD, o = i / KD;
        int ky = kk / 384, r = kk % 384, kx = r >> 7, ic = r & 127;
        wto[i] = (o < 18) ? f2b(wo[((o * CO + ic) * 3 + ky) * 3 + kx]) : f2b(0.f);
        return;
    }
    i -= 32 * KD;
    if (i < CO * KD){
        int kk = i % KD, o = i / KD;
        int kp = kk >> 7, c = kk & 127;
        wtd[i] = f2b(wd[(o * CO + c) * 9 + kp]);
    }
}

// ------------- conv1: A in LDS, B direct global->VGPR (fragment-major) -------------
// 64px x 128oc per block, 4 waves each 64px x 32oc (acc[4][2]). A chunk
// (68px x 128ch, XOR-swizzled) staged once per (ky,ci) group, double-buffered.
// B fragments ping-pong prefetched 1 phase ahead as plain coalesced loads
// (L2-resident). Only 1 barrier per group (10 total) - waves free-run inside.
__global__ __launch_bounds__(256) void k_conv1_mfma(const bf16* __restrict__ catp,
                                                    const bf16* __restrict__ wbt,
                                                    bf16* __restrict__ hp,
                                                    float* __restrict__ sums){
    __shared__ unsigned short Ab[2][68 * 128];   // 2 x 17408 B
    __shared__ float ps[256];
    int t = threadIdx.x;
    int l = t & 63, w = t >> 6;          // w = oc-slice (wn)
    int half = blockIdx.x & 1;
    int y = (blockIdx.x >> 1) % H, b = blockIdx.x / (2 * H);
    int px0 = half * 64;

    int m = l & 15, quad = l >> 4;

    f32x4 acc[4][2];
#pragma unroll
    for (int i = 0; i < 4; i++)
#pragma unroll
        for (int j = 0; j < 2; j++) acc[i][j] = f32x4{0.f, 0.f, 0.f, 0.f};

    const size_t rowStride = (size_t)WP * CCAT;
    const char* wq = (const char*)wbt + w * 2048 + l * 16;

    bf16x8 bA[2][2], bB[2][2];

    // ---- prologue: stage A(0), load B(phase 0) ----
    {
        const bf16* Arow = catp + ((size_t)(b * WP) + y) * rowStride + (size_t)px0 * CCAT;
        for (int i = w; i < 17; i += 4){
            int G = i * 64 + l;
            int px = G >> 4, ol = G & 15;
            int osrc = ol ^ (px & 7);
            async_copy16(Arow + (size_t)px * CCAT + osrc * 8, &Ab[0][i * 512]);
        }
#pragma unroll
        for (int ks = 0; ks < 2; ks++)
#pragma unroll
            for (int ni = 0; ni < 2; ni++)
                bA[ks][ni] = *(const bf16x8*)(wq + ks * 8192 + ni * 1024);
    }
    __syncthreads();

#pragma unroll 1
    for (int g = 0; g < 9; g++){
        if (g < 8){                                   // stage A(g+1) into free buf
            int gn = g + 1;
            int kyn = gn / 3, cin = gn - kyn * 3;
            const bf16* Arow = catp + ((size_t)(b * WP) + y + kyn) * rowStride
                             + (size_t)px0 * CCAT + cin * 128;
            for (int i = w; i < 17; i += 4){
                int G = i * 64 + l;
                int px = G >> 4, ol = G & 15;
                int osrc = ol ^ (px & 7);
                async_copy16(Arow + (size_t)px * CCAT + osrc * 8, &Ab[gn & 1][i * 512]);
            }
        }
        const bf16x8* ap = (const bf16x8*)&Ab[g & 1][0];
        const char* wg = wq + (size_t)g * 6 * 16384;
#pragma unroll
        for (int j = 0; j < 6; j++){
            int kx = j >> 1, s64 = j & 1;
            // prefetch next phase's B (pad covers phase 54 at g=8,j=5)
            const char* wnx = wg + (j + 1) * 16384;
            if (j & 1){
#pragma unroll
                for (int ks = 0; ks < 2; ks++)
#pragma unroll
                    for (int ni = 0; ni < 2; ni++)
                        bA[ks][ni] = *(const bf16x8*)(wnx + ks * 8192 + ni * 1024);
            } else {
#pragma unroll
                for (int ks = 0; ks < 2; ks++)
#pragma unroll
                    for (int ni = 0; ni < 2; ni++)
                        bB[ks][ni] = *(const bf16x8*)(wnx + ks * 8192 + ni * 1024);
            }
#pragma unroll
            for (int ks = 0; ks < 2; ks++){
                int s = s64 * 2 + ks;
                bf16x8 af[4];
#pragma unroll
                for (int mi = 0; mi < 4; mi++){
                    int pxk = mi * 16 + m + kx;
                    af[mi] = ap[pxk * 16 + ((s * 4 + quad) ^ (pxk & 7))];
                }
                if (j & 1){
#pragma unroll
                    for (int mi = 0; mi < 4; mi++)
#pragma unroll
                        for (int ni = 0; ni < 2; ni++)
                            acc[mi][ni] = __builtin_amdgcn_mfma_f32_16x16x32_bf16(
                                af[mi], bB[ks][ni], acc[mi][ni], 0, 0, 0);
                } else {
#pragma unroll
                    for (int mi = 0; mi < 4; mi++)
#pragma unroll
                        for (int ni = 0; ni < 2; ni++)
                            acc[mi][ni] = __builtin_amdgcn_mfma_f32_16x16x32_bf16(
                                af[mi], bA[ks][ni], acc[mi][ni], 0, 0, 0);
                }
            }
        }
        __syncthreads();    // drains A(g+1) staging; frees Ab[g&1] for g+2
    }

    size_t obase = (((size_t)b * WP + y + 1) * WP + 1 + px0) * CO;
#pragma unroll
    for (int mi = 0; mi < 4; mi++){
        int p0 = mi * 16 + quad * 4;
#pragma unroll
        for (int ni = 0; ni < 2; ni++){
            int oc = w * 32 + ni * 16 + m;
#pragma unroll
            for (int r = 0; r < 4; r++)
                hp[obase + (size_t)(p0 + r) * CO + oc] = f2b(acc[mi][ni][r]);
        }
    }
    // fused BN1 stats (shfl quad-reduce -> LDS -> one global atomic per ch)
    ps[t] = 0.f;
    __syncthreads();
#pragma unroll
    for (int ni = 0; ni < 2; ni++){
        int ch = w * 32 + ni * 16 + m;
        float s = 0.f, q2 = 0.f;
#pragma unroll
        for (int mi = 0; mi < 4; mi++)
#pragma unroll
            for (int r = 0; r < 4; r++){
                float v = acc[mi][ni][r];
                s += v; q2 += v * v;
            }
        s += __shfl_xor(s, 16); s += __shfl_xor(s, 32);
        q2 += __shfl_xor(q2, 16); q2 += __shfl_xor(q2, 32);
        if (quad == 0){
            atomicAdd(&ps[ch], s);
            atomicAdd(&ps[128 + ch], q2);
        }
    }
    __syncthreads();
    if (t < 128){
        atomicAdd(&sums[t],       ps[t]);
        atomicAdd(&sums[128 + t], ps[128 + t]);
    }
}

// ------------- BN1 apply + relu in place (scale/shift computed inline) -------------
__global__ __launch_bounds__(256) void k_bn_apply_pad(bf16* __restrict__ t,
                                                      const float* __restrict__ sums,
                                                      const float* __restrict__ g,
                                                      const float* __restrict__ bb){
    __shared__ float ssc[256];
    int tt = threadIdx.x;
    if (tt < 128){
        float mean = sums[tt] / (float)NPIX;
        float var  = sums[128 + tt] / (float)NPIX - mean * mean;
        float scale = g[tt] * rsqrtf(var + EPS);
        ssc[tt]       = scale;
        ssc[128 + tt] = bb[tt] - mean * scale;
    }
    __syncthreads();
    int i = blockIdx.x * 256 + tt;
    if (i >= NPIX * CO) return;
    int c = i & 127;
    int pix = i >> 7;
    int xw = pix & 127, yh = (pix >> 7) & 127, b = pix >> 14;
    size_t a = (((size_t)b * WP + yh + 1) * WP + xw + 1) * CO + c;
    float v = b2f(t[a]) * ssc[c] + ssc[128 + c];
    t[a] = f2b(v > 0.f ? v : 0.f);
}

// ------------- offset conv: row-resident A + per-ky B, MFMA -------------
__global__ __launch_bounds__(256) void k_conv_off_mfma(const bf16* __restrict__ hp,
                                                       const bf16* __restrict__ wob,
                                                       const float* __restrict__ off_b,
                                                       bf16* __restrict__ offs){
    __shared__ unsigned short Ab[132 * 128];   // 33792 B
    __shared__ unsigned short Bb[32 * 384];    // 24576 B
    int t = threadIdx.x, l = t & 63, w = t >> 6;
    int y = blockIdx.x % H, b = blockIdx.x / H;
    int m = l & 15, quad = l >> 4;
    int wm = w & 1, wn = w >> 1;

    f32x4 acc[4];
#pragma unroll
    for (int i = 0; i < 4; i++) acc[i] = f32x4{0.f, 0.f, 0.f, 0.f};

    const size_t rowStrideH = (size_t)WP * CO;
    for (int ky = 0; ky < 3; ky++){
        const bf16* Arow = hp + ((size_t)(b * WP) + y + ky) * rowStrideH;
        __syncthreads();
        for (int i = w; i < 33; i += 4){       // A: full hp row once per ky
            int G  = i * 64 + l;
            int px = G >> 4, ol = G & 15;
            int osrc = ol ^ (px & 7);
            async_copy16(Arow + (size_t)px * CO + osrc * 8, &Ab[i * 512]);
        }
        for (int i = w; i < 24; i += 4){       // B: 32oc x 384k for this ky
            int g  = i * 64 + l;
            int kx = g >> 9, oc = (g >> 4) & 31, ol = g & 15;
            int osrc = ol ^ (oc & 7);
            async_copy16(wob + (size_t)oc * KD + ky * 384 + kx * 128 + osrc * 8,
                         &Bb[i * 512]);
        }
        __syncthreads();
        const bf16x8* ap = (const bf16x8*)Ab;
        const bf16x8* bp = (const bf16x8*)Bb;
        for (int kx = 0; kx < 3; kx++){
#pragma unroll
            for (int s = 0; s < 4; s++){
                int oc = wn * 16 + m;
                bf16x8 bfr = bp[kx * 512 + oc * 16 + ((s * 4 + quad) ^ (oc & 7))];
#pragma unroll
                for (int mi = 0; mi < 4; mi++){
                    int pxk = wm * 64 + mi * 16 + m + kx;
                    bf16x8 af = ap[pxk * 16 + ((s * 4 + quad) ^ (pxk & 7))];
                    acc[mi] = __builtin_amdgcn_mfma_f32_16x16x32_bf16(af, bfr, acc[mi], 0, 0, 0);
                }
            }
        }
    }
    int oc = wn * 16 + m;
    if (oc < 18){
        float bias = off_b[oc];
        int rowpix = b * HW + y * W;
#pragma unroll
        for (int mi = 0; mi < 4; mi++){
            int p0 = wm * 64 + mi * 16 + quad * 4;
#pragma unroll
            for (int r = 0; r < 4; r++)
                offs[(size_t)(rowpix + p0 + r) * 18 + oc] = f2b(acc[mi][r] + bias);
        }
    }
}

// ------------- deform: A-gen in LDS + MFMA GEMM + fused BN2 stats -------------
__global__ __launch_bounds__(256) void k_deform_mfma(const bf16* __restrict__ hp,
                                                     const bf16* __restrict__ offs,
                                                     const bf16* __restrict__ wdb,
                                                     const float* __restrict__ def_b,
                                                     bf16* __restrict__ y,
                                                     float* __restrict__ sums){
    __shared__ unsigned short Ab[128 * 64];
    __shared__ unsigned short Bb[128 * 64];
    __shared__ int2   sc_yx[9 * 128];
    __shared__ float4 sc_w[9 * 128];
    __shared__ float  ps[256];

    int t = threadIdx.x, l = t & 63, w = t >> 6;
    int yrow = blockIdx.x % H, b = blockIdx.x / H;
    int rowpix = b * HW + yrow * W;

    for (int idx = t; idx < 9 * 128; idx += 256){
        int kp = idx >> 7, px = idx & 127;
        float dy = b2f(offs[(size_t)(rowpix + px) * 18 + 2 * kp]);
        float dx = b2f(offs[(size_t)(rowpix + px) * 18 + 2 * kp + 1]);
        float py = yrow + (kp / 3 - 1) + dy;
        float pxx = px + (kp % 3 - 1) + dx;
        float fy = floorf(py), fx = floorf(pxx);
        float wy = py - fy, wx = pxx - fx;
        int y0 = (int)fy, x0 = (int)fx;
        bool vy0 = (y0 >= 0) && (y0 < H);
        bool vy1 = (y0 + 1 >= 0) && (y0 + 1 < H);
        bool vx0 = (x0 >= 0) && (x0 < W);
        bool vx1 = (x0 + 1 >= 0) && (x0 + 1 < W);
        int y0c = min(max(y0, 0), H - 1),     y1c = min(max(y0 + 1, 0), H - 1);
        int x0c = min(max(x0, 0), W - 1),     x1c = min(max(x0 + 1, 0), W - 1);
        sc_yx[idx] = make_int2(((y0c + 1) * WP) | (((y1c + 1) * WP) << 16),
                               (x0c + 1) | ((x1c + 1) << 16));
        sc_w[idx] = make_float4((1 - wy) * (1 - wx) * (float)(vy0 && vx0),
                                (1 - wy) * wx       * (float)(vy0 && vx1),
                                wy * (1 - wx)       * (float)(vy1 && vx0),
                                wy * wx             * (float)(vy1 && vx1));
    }
    __syncthreads();

    int pr = l >> 3, koct = (l & 7) ^ pr;
    int m = l & 15, quad = l >> 4;
    int wm = w & 1, wn = w >> 1;
    int g = l >> 4, j = l & 15;

    f32x4 acc[4][4];
#pragma unroll
    for (int i = 0; i < 4; i++)
#pragma unroll
        for (int jj = 0; jj < 4; jj++) acc[i][jj] = f32x4{0.f, 0.f, 0.f, 0.f};

    const bf16* hpb = hp + (size_t)b * WP * WP * CO;

    for (int kc = 0; kc < 18; kc++){
        int kp = kc >> 1, ch = (kc & 1) * 64;
        __syncthreads();
        int kg = kp * 128 + ch;
#pragma unroll
        for (int i = 0; i < 4; i++){
            int oc = w * 32 + i * 8 + pr;
            async_copy16(wdb + (size_t)oc * KD + kg + koct * 8,
                         &Bb[(w * 32 + i * 8) * 64]);
        }
        int cb = ch + j * 4;
#pragma unroll
        for (int p = 0; p < 8; p++){
            int px = w * 32 + g * 8 + p;
            int idx = kp * 128 + px;
            int2 yx = sc_yx[idx];
            float4 w4 = sc_w[idx];
            int r0 = yx.x & 0xffff, r1 = ((unsigned)yx.x) >> 16;
            int c0 = yx.y & 0xffff, c1 = ((unsigned)yx.y) >> 16;
            const bf16* base = hpb + cb;
            bf16x4 s00 = *(const bf16x4*)(base + (size_t)(r0 + c0) * CO);
            bf16x4 s01 = *(const bf16x4*)(base + (size_t)(r0 + c1) * CO);
            bf16x4 s10 = *(const bf16x4*)(base + (size_t)(r1 + c0) * CO);
            bf16x4 s11 = *(const bf16x4*)(base + (size_t)(r1 + c1) * CO);
            bf16x4 pv;
#pragma unroll
            for (int r = 0; r < 4; r++){
                float v = w4.x * (float)s00[r] + w4.y * (float)s01[r]
                        + w4.z * (float)s10[r] + w4.w * (float)s11[r];
                pv[r] = (__bf16)v;
            }
            int oct_sw = (j >> 1) ^ (px & 7);
            *(bf16x4*)&Ab[px * 64 + oct_sw * 8 + (j & 1) * 4] = pv;
        }
        __syncthreads();
        const bf16x8* ap = (const bf16x8*)Ab;
        const bf16x8* bp = (const bf16x8*)Bb;
#pragma unroll
        for (int ks = 0; ks < 2; ks++){
            bf16x8 af[4], bfr[4];
#pragma unroll
            for (int mi = 0; mi < 4; mi++){
                int px = wm * 64 + mi * 16 + m;
                af[mi] = ap[px * 8 + ((ks * 4 + quad) ^ (px & 7))];
            }
#pragma unroll
            for (int ni = 0; ni < 4; ni++){
                int oc = wn * 64 + ni * 16 + m;
                bfr[ni] = bp[oc * 8 + ((ks * 4 + quad) ^ (oc & 7))];
            }
#pragma unroll
            for (int mi = 0; mi < 4; mi++)
#pragma unroll
                for (int ni = 0; ni < 4; ni++)
                    acc[mi][ni] = __builtin_amdgcn_mfma_f32_16x16x32_bf16(
                        af[mi], bfr[ni], acc[mi][ni], 0, 0, 0);
        }
    }
#pragma unroll
    for (int mi = 0; mi < 4; mi++){
        int p0 = wm * 64 + mi * 16 + quad * 4;
#pragma unroll
        for (int ni = 0; ni < 4; ni++){
            int oc = wn * 64 + ni * 16 + m;
            float bias = def_b[oc];
#pragma unroll
            for (int r = 0; r < 4; r++)
                y[(size_t)(rowpix + p0 + r) * CO + oc] = f2b(acc[mi][ni][r] + bias);
        }
    }
    // fused BN2 stats (shfl quad-reduction)
    ps[t] = 0.f;
    __syncthreads();
#pragma unroll
    for (int ni = 0; ni < 4; ni++){
        int ch = wn * 64 + ni * 16 + m;
        float bias = def_b[ch];
        float s = 0.f, q = 0.f;
#pragma unroll
        for (int mi = 0; mi < 4; mi++)
#pragma unroll
            for (int r = 0; r < 4; r++){
                float v = acc[mi][ni][r] + bias;
                s += v; q += v * v;
            }
        s += __shfl_xor(s, 16); s += __shfl_xor(s, 32);
        q += __shfl_xor(q, 16); q += __shfl_xor(q, 32);
        if (quad == 0){
            atomicAdd(&ps[ch], s);
            atomicAdd(&ps[128 + ch], q);
        }
    }
    __syncthreads();
    if (t < 128){
        atomicAdd(&sums[t],       ps[t]);
        atomicAdd(&sums[128 + t], ps[128 + t]);
    }
}

// ------------- BN2 apply + relu + NHWC->NCHW (scale/shift inline) -------------
__global__ __launch_bounds__(256) void k_final(const bf16* __restrict__ yb,
                                               const float* __restrict__ sums,
                                               const float* __restrict__ g,
                                               const float* __restrict__ bb,
                                               float* __restrict__ out){
    __shared__ unsigned short tile[128 * 129];
    __shared__ float ssc[256];
    int t = threadIdx.x;
    if (t < 128){
        float mean = sums[t] / (float)NPIX;
        float var  = sums[128 + t] / (float)NPIX - mean * mean;
        float scale = g[t] * rsqrtf(var + EPS);
        ssc[t]       = scale;
        ssc[128 + t] = bb[t] - mean * scale;
    }
    int yrow = blockIdx.x % H, b = blockIdx.x / H;
    int rowbase = b * HW + yrow * W;
    const unsigned short* src = (const unsigned short*)yb;
    for (int it = 0; it < 64; it++){
        int idx = it * 256 + t;
        int c = idx & 127, px = idx >> 7;
        tile[px * 129 + c] = src[(size_t)(rowbase + px) * CO + c];
    }
    __syncthreads();
    for (int it = 0; it < 64; it++){
        int idx = it * 256 + t;
        int xw = idx & 127, o = idx >> 7;
        unsigned short u = tile[xw * 129 + o];
        float v = (float)(*(const __bf16*)&u);
        v = v * ssc[o] + ssc[128 + o];
        out[(((size_t)b * CO + o) * H + yrow) * W + xw] = v > 0.f ? v : 0.f;
    }
}

extern "C" void kernel_launch(void* const* d_in, const int* in_sizes, int n_in,
                              void* d_out, int out_size, void* d_ws, size_t ws_size,
                              hipStream_t stream){
    const float* x      = (const float*)d_in[0];
    const float* skip   = (const float*)d_in[1];
    const float* conv1w = (const float*)d_in[2];
    const float* bn1g   = (const float*)d_in[3];
    const float* bn1b   = (const float*)d_in[4];
    const float* offw   = (const float*)d_in[5];
    const float* offb   = (const float*)d_in[6];
    const float* defw   = (const float*)d_in[7];
    const float* defb   = (const float*)d_in[8];
    const float* bn2g   = (const float*)d_in[9];
    const float* bn2b   = (const float*)d_in[10];
    float* out = (float*)d_out;

    char* ws = (char*)d_ws;
    size_t off_bytes = 0;
    auto alloc = [&](size_t bytes) -> void* {
        void* p = ws + off_bytes;
        off_bytes += (bytes + 255) & ~(size_t)255;
        return p;
    };
    const size_t catp_elems = (size_t)NB * WP * WP * CCAT;
    const size_t hp_elems   = (size_t)NB * WP * WP * CO;
    bf16*  catp  = (bf16*) alloc(catp_elems * 2 + 2048);     // +tail pad for 2px overread
    bf16*  hp    = (bf16*) alloc(hp_elems * 2);              // 17.3 MB
    bf16*  offs  = (bf16*) alloc((size_t)NPIX * 18 * 2);
    bf16*  yb    = (bf16*) alloc((size_t)NPIX * CO * 2);
    bf16*  wbt   = (bf16*) alloc((size_t)CO * K1 * 2 + 32768); // +pad: phase-54 prefetch overread
    bf16*  wob   = (bf16*) alloc((size_t)32 * KD * 2);
    bf16*  wdb   = (bf16*) alloc((size_t)CO * KD * 2);
    float* sums  = (float*)alloc(512 * 4);
    float* sums1 = sums;
    float* sums2 = sums + 256;

    k_prep<<<1024, 256, 0, stream>>>(sums, catp, hp);

    k_build_cat2<<<NB * H, 256, 0, stream>>>(x, skip, catp);

    const int ntr = CO * K1 + 32 * KD + CO * KD;
    k_tr_all<<<(ntr + 255) / 256, 256, 0, stream>>>(conv1w, offw, defw, wbt, wob, wdb);

    k_conv1_mfma<<<NB * H * 2, 256, 0, stream>>>(catp, wbt, hp, sums1);

    k_bn_apply_pad<<<(NPIX * CO + 255) / 256, 256, 0, stream>>>(hp, sums1, bn1g, bn1b);

    k_conv_off_mfma<<<NB * H, 256, 0, stream>>>(hp, wob, offb, offs);

    k_deform_mfma<<<NB * H, 256, 0, stream>>>(hp, offs, wdb, defb, yb, sums2);

    k_final<<<NB * H, 256, 0, stream>>>(yb, sums2, bn2g, bn2b, out);
}

// Round 5
// 332.557 us; speedup vs baseline: 1.1176x; 1.0039x over previous
//
#include <hip/hip_runtime.h>
#include <hip/hip_bf16.h>

typedef __hip_bfloat16 bf16;
typedef __bf16 bf16x8 __attribute__((ext_vector_type(8)));
typedef __bf16 bf16x4 __attribute__((ext_vector_type(4)));
typedef float  f32x4  __attribute__((ext_vector_type(4)));

constexpr int NB   = 4;
constexpr int H    = 128;
constexpr int W    = 128;
constexpr int HW   = H * W;
constexpr int NPIX = NB * HW;        // 65536
constexpr int CCAT = 384;
constexpr int CSKIP= 128;
constexpr int CIN  = 256;
constexpr int CO   = 128;
constexpr int HS   = 64;
constexpr int WP   = 130;            // padded H/W
constexpr int K1   = 3456;           // conv1 GEMM K
constexpr int KD   = 1152;           // deform/off GEMM K
constexpr int NBORD= 2 * WP + 2 * (WP - 2);   // 516 border px per image
constexpr float EPS = 1e-5f;

__device__ __forceinline__ float b2f(bf16 v){ return __bfloat162float(v); }
__device__ __forceinline__ bf16  f2b(float v){ return __float2bfloat16(v); }

__device__ __forceinline__ void async_copy16(const void* g, void* s){
    __builtin_amdgcn_global_load_lds((const __attribute__((address_space(1))) void*)g,
                                     (__attribute__((address_space(3))) void*)s, 16, 0, 0);
}

// map border index 0..515 -> (y,x) on the WPxWP frame
__device__ __forceinline__ void border_yx(int p, int& y, int& x){
    if (p < WP)             { y = 0;        x = p; }
    else if (p < 2 * WP)    { y = WP - 1;   x = p - WP; }
    else if (p < 2 * WP + (WP - 2)) { y = p - 2 * WP + 1;          x = 0; }
    else                    { y = p - (2 * WP + (WP - 2)) + 1;     x = WP - 1; }
}

// ------------- prep: zero stat buffers + padded borders -------------
__global__ void k_prep(float* __restrict__ sums, bf16* __restrict__ catp,
                       bf16* __restrict__ hp){
    int i = blockIdx.x * blockDim.x + threadIdx.x;
    int stride = gridDim.x * blockDim.x;
    for (int j = i; j < 512; j += stride) sums[j] = 0.f;
    const int nCat = NB * NBORD * CCAT;
    for (int j = i; j < nCat; j += stride){
        int c = j % CCAT, r = j / CCAT, p = r % NBORD, b = r / NBORD;
        int y, x; border_yx(p, y, x);
        catp[(((size_t)b * WP + y) * WP + x) * CCAT + c] = f2b(0.f);
    }
    const int nHp = NB * NBORD * CO;
    for (int j = i; j < nHp; j += stride){
        int c = j % CO, r = j / CO, p = r % NBORD, b = r / NBORD;
        int y, x; border_yx(p, y, x);
        hp[(((size_t)b * WP + y) * WP + x) * CO + c] = f2b(0.f);
    }
}

// ------------- build cat interior via LDS transpose -------------
__global__ __launch_bounds__(256) void k_build_cat2(const float* __restrict__ x,
                                                    const float* __restrict__ skip,
                                                    bf16* __restrict__ catp){
    constexpr int TS = 66;
    __shared__ bf16 tile[128 * TS];
    int t  = threadIdx.x;
    int y  = blockIdx.x % H, b = blockIdx.x / H;
    int xx = t & 127, cp = t >> 7;

    float cy = (y * 63.0f) / 127.0f;
    int   y0 = (int)cy;
    int   y1 = min(y0 + 1, HS - 1);
    float wy = cy - y0;
    float cxf = (xx * 63.0f) / 127.0f;
    int   x0 = (int)cxf;
    int   x1 = min(x0 + 1, HS - 1);
    float wx = cxf - x0;

    bf16* orow = catp + (((size_t)b * WP + y + 1) * WP + 1) * CCAT;

    for (int chunk = 0; chunk < 6; chunk++){
        int cbase = chunk * 64;
        if (chunk >= 1) __syncthreads();
        if (chunk < 2){
            const float* sb = skip + ((size_t)(b * CSKIP + cbase + cp * 32) * H + y) * W;
#pragma unroll
            for (int i = 0; i < 32; i++)
                tile[xx * TS + cp * 32 + i] = f2b(sb[(size_t)i * HW + xx]);
        } else {
            int icb = (chunk - 2) * 64 + cp * 32;
            const float* xr0 = x + ((size_t)(b * CIN + icb) * HS + y0) * HS;
            const float* xr1 = x + ((size_t)(b * CIN + icb) * HS + y1) * HS;
#pragma unroll
            for (int i = 0; i < 32; i++){
                const float* r0 = xr0 + (size_t)i * HS * HS;
                const float* r1 = xr1 + (size_t)i * HS * HS;
                float v0 = r0[x0] * (1 - wx) + r0[x1] * wx;
                float v1 = r1[x0] * (1 - wx) + r1[x1] * wx;
                tile[xx * TS + cp * 32 + i] = f2b(v0 * (1 - wy) + v1 * wy);
            }
        }
        __syncthreads();
        int cc2 = (t & 31) * 2;
        int px0 = t >> 5;
#pragma unroll
        for (int pp = 0; pp < 16; pp++){
            int px = pp * 8 + px0;
            unsigned int v = *(const unsigned int*)&tile[px * TS + cc2];
            *(unsigned int*)&orow[(size_t)px * CCAT + cbase + cc2] = v;
        }
    }
}

// ------------- all weight transposes in one kernel -------------
// ALL THREE weight tensors emitted FRAGMENT-MAJOR so MFMA B-operands are
// plain coalesced 16B/lane global loads (no LDS round-trip):
//  wt1 (conv1):  [p54][ks2][nb8][l64][e8]
//  wto (off):    [kk9][s4][wn2][l64][e8]
//  wtd (deform): [kc18][ks2][wn2][ni4][l64][e8]
__global__ void k_tr_all(const float* __restrict__ w1, const float* __restrict__ wo,
                         const float* __restrict__ wd,
                         bf16* __restrict__ wt1, bf16* __restrict__ wto,
                         bf16* __restrict__ wtd){
    int i = blockIdx.x * blockDim.x + threadIdx.x;
    if (i < CO * K1){
        int e  = i & 7;
        int l  = (i >> 3) & 63;
        int nb = (i >> 9) & 7;
        int ks = (i >> 12) & 1;
        int p  = i >> 13;                 // 0..53
        int gp = p / 6, q = p - gp * 6;
        int ky = gp / 3, ci = gp - ky * 3;
        int kx = q >> 1, s64 = q & 1;
        int oc = nb * 16 + (l & 15);
        int ic = ci * 128 + s64 * 64 + ks * 32 + (l >> 4) * 8 + e;
        wt1[i] = f2b(w1[((oc * CCAT + ic) * 3 + ky) * 3 + kx]);
        return;
    }
    i -= CO * K1;
    if (i < 32 * KD){
        int e  = i & 7;
        int l  = (i >> 3) & 63;
        int wn = (i >> 9) & 1;
        int s  = (i >> 10) & 3;
        int kk = i >> 12;                 // 0..8
        int ky = kk / 3, kx = kk - ky * 3;
        int oc = wn * 16 + (l & 15);
        int ic = s * 32 + (l >> 4) * 8 + e;
        wto[i] = (oc < 18) ? f2b(wo[((oc * CO + ic) * 3 + ky) * 3 + kx]) : f2b(0.f);
        return;
    }
    i -= 32 * KD;
    if (i < CO * KD){
        int e  = i & 7;
        int l  = (i >> 3) & 63;
        int ni = (i >> 9) & 3;
        int wn = (i >> 11) & 1;
        int ks = (i >> 12) & 1;
        int kc = i >> 13;                 // 0..17
        int oc = wn * 64 + ni * 16 + (l & 15);
        int ic = (kc & 1) * 64 + ks * 32 + (l >> 4) * 8 + e;
        int kp = kc >> 1;
        wtd[i] = f2b(wd[(oc * CO + ic) * 9 + kp]);
    }
}

// ------------- conv1: A in LDS, B direct global->VGPR (fragment-major) -------------
// (unchanged from R4 — conv1 is locally converged at ~87us)
__global__ __launch_bounds__(256) void k_conv1_mfma(const bf16* __restrict__ catp,
                                                    const bf16* __restrict__ wbt,
                                                    bf16* __restrict__ hp,
                                                    float* __restrict__ sums){
    __shared__ unsigned short Ab[2][68 * 128];   // 2 x 17408 B
    __shared__ float ps[256];
    int t = threadIdx.x;
    int l = t & 63, w = t >> 6;          // w = oc-slice (wn)
    int half = blockIdx.x & 1;
    int y = (blockIdx.x >> 1) % H, b = blockIdx.x / (2 * H);
    int px0 = half * 64;

    int m = l & 15, quad = l >> 4;

    f32x4 acc[4][2];
#pragma unroll
    for (int i = 0; i < 4; i++)
#pragma unroll
        for (int j = 0; j < 2; j++) acc[i][j] = f32x4{0.f, 0.f, 0.f, 0.f};

    const size_t rowStride = (size_t)WP * CCAT;
    const char* wq = (const char*)wbt + w * 2048 + l * 16;

    bf16x8 bA[2][2], bB[2][2];

    {
        const bf16* Arow = catp + ((size_t)(b * WP) + y) * rowStride + (size_t)px0 * CCAT;
        for (int i = w; i < 17; i += 4){
            int G = i * 64 + l;
            int px = G >> 4, ol = G & 15;
            int osrc = ol ^ (px & 7);
            async_copy16(Arow + (size_t)px * CCAT + osrc * 8, &Ab[0][i * 512]);
        }
#pragma unroll
        for (int ks = 0; ks < 2; ks++)
#pragma unroll
            for (int ni = 0; ni < 2; ni++)
                bA[ks][ni] = *(const bf16x8*)(wq + ks * 8192 + ni * 1024);
    }
    __syncthreads();

#pragma unroll 1
    for (int g = 0; g < 9; g++){
        if (g < 8){
            int gn = g + 1;
            int kyn = gn / 3, cin = gn - kyn * 3;
            const bf16* Arow = catp + ((size_t)(b * WP) + y + kyn) * rowStride
                             + (size_t)px0 * CCAT + cin * 128;
            for (int i = w; i < 17; i += 4){
                int G = i * 64 + l;
                int px = G >> 4, ol = G & 15;
                int osrc = ol ^ (px & 7);
                async_copy16(Arow + (size_t)px * CCAT + osrc * 8, &Ab[gn & 1][i * 512]);
            }
        }
        const bf16x8* ap = (const bf16x8*)&Ab[g & 1][0];
        const char* wg = wq + (size_t)g * 6 * 16384;
#pragma unroll
        for (int j = 0; j < 6; j++){
            int kx = j >> 1, s64 = j & 1;
            const char* wnx = wg + (j + 1) * 16384;
            if (j & 1){
#pragma unroll
                for (int ks = 0; ks < 2; ks++)
#pragma unroll
                    for (int ni = 0; ni < 2; ni++)
                        bA[ks][ni] = *(const bf16x8*)(wnx + ks * 8192 + ni * 1024);
            } else {
#pragma unroll
                for (int ks = 0; ks < 2; ks++)
#pragma unroll
                    for (int ni = 0; ni < 2; ni++)
                        bB[ks][ni] = *(const bf16x8*)(wnx + ks * 8192 + ni * 1024);
            }
#pragma unroll
            for (int ks = 0; ks < 2; ks++){
                int s = s64 * 2 + ks;
                bf16x8 af[4];
#pragma unroll
                for (int mi = 0; mi < 4; mi++){
                    int pxk = mi * 16 + m + kx;
                    af[mi] = ap[pxk * 16 + ((s * 4 + quad) ^ (pxk & 7))];
                }
                if (j & 1){
#pragma unroll
                    for (int mi = 0; mi < 4; mi++)
#pragma unroll
                        for (int ni = 0; ni < 2; ni++)
                            acc[mi][ni] = __builtin_amdgcn_mfma_f32_16x16x32_bf16(
                                af[mi], bB[ks][ni], acc[mi][ni], 0, 0, 0);
                } else {
#pragma unroll
                    for (int mi = 0; mi < 4; mi++)
#pragma unroll
                        for (int ni = 0; ni < 2; ni++)
                            acc[mi][ni] = __builtin_amdgcn_mfma_f32_16x16x32_bf16(
                                af[mi], bA[ks][ni], acc[mi][ni], 0, 0, 0);
                }
            }
        }
        __syncthreads();
    }

    size_t obase = (((size_t)b * WP + y + 1) * WP + 1 + px0) * CO;
#pragma unroll
    for (int mi = 0; mi < 4; mi++){
        int p0 = mi * 16 + quad * 4;
#pragma unroll
        for (int ni = 0; ni < 2; ni++){
            int oc = w * 32 + ni * 16 + m;
#pragma unroll
            for (int r = 0; r < 4; r++)
                hp[obase + (size_t)(p0 + r) * CO + oc] = f2b(acc[mi][ni][r]);
        }
    }
    ps[t] = 0.f;
    __syncthreads();
#pragma unroll
    for (int ni = 0; ni < 2; ni++){
        int ch = w * 32 + ni * 16 + m;
        float s = 0.f, q2 = 0.f;
#pragma unroll
        for (int mi = 0; mi < 4; mi++)
#pragma unroll
            for (int r = 0; r < 4; r++){
                float v = acc[mi][ni][r];
                s += v; q2 += v * v;
            }
        s += __shfl_xor(s, 16); s += __shfl_xor(s, 32);
        q2 += __shfl_xor(q2, 16); q2 += __shfl_xor(q2, 32);
        if (quad == 0){
            atomicAdd(&ps[ch], s);
            atomicAdd(&ps[128 + ch], q2);
        }
    }
    __syncthreads();
    if (t < 128){
        atomicAdd(&sums[t],       ps[t]);
        atomicAdd(&sums[128 + t], ps[128 + t]);
    }
}

// ------------- BN1 apply + relu in place (scale/shift computed inline) -------------
__global__ __launch_bounds__(256) void k_bn_apply_pad(bf16* __restrict__ t,
                                                      const float* __restrict__ sums,
                                                      const float* __restrict__ g,
                                                      const float* __restrict__ bb){
    __shared__ float ssc[256];
    int tt = threadIdx.x;
    if (tt < 128){
        float mean = sums[tt] / (float)NPIX;
        float var  = sums[128 + tt] / (float)NPIX - mean * mean;
        float scale = g[tt] * rsqrtf(var + EPS);
        ssc[tt]       = scale;
        ssc[128 + tt] = bb[tt] - mean * scale;
    }
    __syncthreads();
    int i = blockIdx.x * 256 + tt;
    if (i >= NPIX * CO) return;
    int c = i & 127;
    int pix = i >> 7;
    int xw = pix & 127, yh = (pix >> 7) & 127, b = pix >> 14;
    size_t a = (((size_t)b * WP + yh + 1) * WP + xw + 1) * CO + c;
    float v = b2f(t[a]) * ssc[c] + ssc[128 + c];
    t[a] = f2b(v > 0.f ? v : 0.f);
}

// ------------- offset conv: 64px blocks, A in LDS, B global->VGPR -------------
// Each block: 64px x 32oc, 4 waves = 2px-half x 2oc-half, wave = 32px x 16oc.
// LDS 17.4KB -> 4 blocks/CU (was 2). B fragments (12 b128/wave) loaded from
// fragment-major wto; no B LDS staging, 5 barriers total.
__global__ __launch_bounds__(256) void k_conv_off_mfma(const bf16* __restrict__ hp,
                                                       const bf16* __restrict__ wob,
                                                       const float* __restrict__ off_b,
                                                       bf16* __restrict__ offs){
    __shared__ unsigned short Ab[68 * 128];    // 17408 B
    int t = threadIdx.x, l = t & 63, w = t >> 6;
    int half = blockIdx.x & 1;
    int y = (blockIdx.x >> 1) % H, b = blockIdx.x / (2 * H);
    int px0 = half * 64;
    int m = l & 15, quad = l >> 4;
    int wm = w & 1, wn = w >> 1;

    f32x4 acc[2];
#pragma unroll
    for (int i = 0; i < 2; i++) acc[i] = f32x4{0.f, 0.f, 0.f, 0.f};

    const size_t rowStrideH = (size_t)WP * CO;
    const char* wq = (const char*)wob + wn * 1024 + l * 16;

    for (int ky = 0; ky < 3; ky++){
        if (ky) __syncthreads();               // prior readers of Ab done
        const bf16* Arow = hp + ((size_t)(b * WP) + y + ky) * rowStrideH
                         + (size_t)px0 * CO;
        for (int i = w; i < 17; i += 4){       // A: 68px x 128ch
            int G  = i * 64 + l;
            int px = G >> 4, ol = G & 15;
            int osrc = ol ^ (px & 7);
            async_copy16(Arow + (size_t)px * CO + osrc * 8, &Ab[i * 512]);
        }
        bf16x8 bfr[3][4];                      // B frags for this ky (global)
#pragma unroll
        for (int kx = 0; kx < 3; kx++)
#pragma unroll
            for (int s = 0; s < 4; s++)
                bfr[kx][s] = *(const bf16x8*)(wq + (((ky * 3 + kx) * 4 + s) * 2048));
        __syncthreads();                       // staging drained (vmcnt0+barrier)
        const bf16x8* ap = (const bf16x8*)Ab;
        for (int kx = 0; kx < 3; kx++){
#pragma unroll
            for (int s = 0; s < 4; s++){
#pragma unroll
                for (int mi = 0; mi < 2; mi++){
                    int pxk = wm * 32 + mi * 16 + m + kx;
                    bf16x8 af = ap[pxk * 16 + ((s * 4 + quad) ^ (pxk & 7))];
                    acc[mi] = __builtin_amdgcn_mfma_f32_16x16x32_bf16(af, bfr[kx][s], acc[mi], 0, 0, 0);
                }
            }
        }
    }
    int oc = wn * 16 + m;
    if (oc < 18){
        float bias = off_b[oc];
        int rowpix = b * HW + y * W + px0;
#pragma unroll
        for (int mi = 0; mi < 2; mi++){
            int p0 = wm * 32 + mi * 16 + quad * 4;
#pragma unroll
            for (int r = 0; r < 4; r++)
                offs[(size_t)(rowpix + p0 + r) * 18 + oc] = f2b(acc[mi][r] + bias);
        }
    }
}

// ------------- deform: dbuf A-gen overlapped with MFMA, B global->VGPR -------------
// Per kc: {sync; issue B-frag loads (global, fragment-major); GEN(kc+1) into
// the other A buffer (VALU+gather covers B latency); MFMA(kc)}. One barrier
// per kc (18 total, was 36); B LDS staging eliminated (-288KB/block).
__global__ __launch_bounds__(256) void k_deform_mfma(const bf16* __restrict__ hp,
                                                     const bf16* __restrict__ offs,
                                                     const bf16* __restrict__ wdb,
                                                     const float* __restrict__ def_b,
                                                     bf16* __restrict__ y,
                                                     float* __restrict__ sums){
    __shared__ unsigned short Ab[2][128 * 64];
    __shared__ int2   sc_yx[9 * 128];
    __shared__ float4 sc_w[9 * 128];
    __shared__ float  ps[256];

    int t = threadIdx.x, l = t & 63, w = t >> 6;
    int yrow = blockIdx.x % H, b = blockIdx.x / H;
    int rowpix = b * HW + yrow * W;

    for (int idx = t; idx < 9 * 128; idx += 256){
        int kp = idx >> 7, px = idx & 127;
        float dy = b2f(offs[(size_t)(rowpix + px) * 18 + 2 * kp]);
        float dx = b2f(offs[(size_t)(rowpix + px) * 18 + 2 * kp + 1]);
        float py = yrow + (kp / 3 - 1) + dy;
        float pxx = px + (kp % 3 - 1) + dx;
        float fy = floorf(py), fx = floorf(pxx);
        float wy = py - fy, wx = pxx - fx;
        int y0 = (int)fy, x0 = (int)fx;
        bool vy0 = (y0 >= 0) && (y0 < H);
        bool vy1 = (y0 + 1 >= 0) && (y0 + 1 < H);
        bool vx0 = (x0 >= 0) && (x0 < W);
        bool vx1 = (x0 + 1 >= 0) && (x0 + 1 < W);
        int y0c = min(max(y0, 0), H - 1),     y1c = min(max(y0 + 1, 0), H - 1);
        int x0c = min(max(x0, 0), W - 1),     x1c = min(max(x0 + 1, 0), W - 1);
        sc_yx[idx] = make_int2(((y0c + 1) * WP) | (((y1c + 1) * WP) << 16),
                               (x0c + 1) | ((x1c + 1) << 16));
        sc_w[idx] = make_float4((1 - wy) * (1 - wx) * (float)(vy0 && vx0),
                                (1 - wy) * wx       * (float)(vy0 && vx1),
                                wy * (1 - wx)       * (float)(vy1 && vx0),
                                wy * wx             * (float)(vy1 && vx1));
    }
    __syncthreads();

    int m = l & 15, quad = l >> 4;
    int wm = w & 1, wn = w >> 1;
    int g = l >> 4, j = l & 15;

    f32x4 acc[4][4];
#pragma unroll
    for (int i = 0; i < 4; i++)
#pragma unroll
        for (int jj = 0; jj < 4; jj++) acc[i][jj] = f32x4{0.f, 0.f, 0.f, 0.f};

    const bf16* hpb = hp + (size_t)b * WP * WP * CO;
    const char* wq = (const char*)wdb + wn * 4096 + l * 16;

    // A-gen for k-chunk kc into buffer buf
    auto GEN = [&](int kc, unsigned short* dst){
        int kp = kc >> 1, ch = (kc & 1) * 64;
        int cb = ch + j * 4;
#pragma unroll
        for (int p = 0; p < 8; p++){
            int px = w * 32 + g * 8 + p;
            int idx = kp * 128 + px;
            int2 yx = sc_yx[idx];
            float4 w4 = sc_w[idx];
            int r0 = yx.x & 0xffff, r1 = ((unsigned)yx.x) >> 16;
            int c0 = yx.y & 0xffff, c1 = ((unsigned)yx.y) >> 16;
            const bf16* base = hpb + cb;
            bf16x4 s00 = *(const bf16x4*)(base + (size_t)(r0 + c0) * CO);
            bf16x4 s01 = *(const bf16x4*)(base + (size_t)(r0 + c1) * CO);
            bf16x4 s10 = *(const bf16x4*)(base + (size_t)(r1 + c0) * CO);
            bf16x4 s11 = *(const bf16x4*)(base + (size_t)(r1 + c1) * CO);
            bf16x4 pv;
#pragma unroll
            for (int r = 0; r < 4; r++){
                float v = w4.x * (float)s00[r] + w4.y * (float)s01[r]
                        + w4.z * (float)s10[r] + w4.w * (float)s11[r];
                pv[r] = (__bf16)v;
            }
            int oct_sw = (j >> 1) ^ (px & 7);
            *(bf16x4*)&dst[px * 64 + oct_sw * 8 + (j & 1) * 4] = pv;
        }
    };

    GEN(0, &Ab[0][0]);

#pragma unroll 1
    for (int kc = 0; kc < 18; kc++){
        __syncthreads();                       // Ab[kc&1] writes visible; prev reads done
        // B fragments for kc (global, fragment-major) — issue early
        bf16x8 bfr[2][4];
        const char* wk = wq + (size_t)kc * 16384;
#pragma unroll
        for (int ks = 0; ks < 2; ks++)
#pragma unroll
            for (int ni = 0; ni < 4; ni++)
                bfr[ks][ni] = *(const bf16x8*)(wk + ks * 8192 + ni * 1024);
        // overlap: generate next chunk's A while B lands / MFMA runs
        if (kc < 17) GEN(kc + 1, &Ab[(kc + 1) & 1][0]);

        const bf16x8* ap = (const bf16x8*)&Ab[kc & 1][0];
#pragma unroll
        for (int ks = 0; ks < 2; ks++){
            bf16x8 af[4];
#pragma unroll
            for (int mi = 0; mi < 4; mi++){
                int px = wm * 64 + mi * 16 + m;
                af[mi] = ap[px * 8 + ((ks * 4 + quad) ^ (px & 7))];
            }
#pragma unroll
            for (int mi = 0; mi < 4; mi++)
#pragma unroll
                for (int ni = 0; ni < 4; ni++)
                    acc[mi][ni] = __builtin_amdgcn_mfma_f32_16x16x32_bf16(
                        af[mi], bfr[ks][ni], acc[mi][ni], 0, 0, 0);
        }
    }
#pragma unroll
    for (int mi = 0; mi < 4; mi++){
        int p0 = wm * 64 + mi * 16 + quad * 4;
#pragma unroll
        for (int ni = 0; ni < 4; ni++){
            int oc = wn * 64 + ni * 16 + m;
            float bias = def_b[oc];
#pragma unroll
            for (int r = 0; r < 4; r++)
                y[(size_t)(rowpix + p0 + r) * CO + oc] = f2b(acc[mi][ni][r] + bias);
        }
    }
    // fused BN2 stats (shfl quad-reduction)
    ps[t] = 0.f;
    __syncthreads();
#pragma unroll
    for (int ni = 0; ni < 4; ni++){
        int ch = wn * 64 + ni * 16 + m;
        float bias = def_b[ch];
        float s = 0.f, q = 0.f;
#pragma unroll
        for (int mi = 0; mi < 4; mi++)
#pragma unroll
            for (int r = 0; r < 4; r++){
                float v = acc[mi][ni][r] + bias;
                s += v; q += v * v;
            }
        s += __shfl_xor(s, 16); s += __shfl_xor(s, 32);
        q += __shfl_xor(q, 16); q += __shfl_xor(q, 32);
        if (quad == 0){
            atomicAdd(&ps[ch], s);
            atomicAdd(&ps[128 + ch], q);
        }
    }
    __syncthreads();
    if (t < 128){
        atomicAdd(&sums[t],       ps[t]);
        atomicAdd(&sums[128 + t], ps[128 + t]);
    }
}

// ------------- BN2 apply + relu + NHWC->NCHW (scale/shift inline) -------------
__global__ __launch_bounds__(256) void k_final(const bf16* __restrict__ yb,
                                               const float* __restrict__ sums,
                                               const float* __restrict__ g,
                                               const float* __restrict__ bb,
                                               float* __restrict__ out){
    __shared__ unsigned short tile[128 * 129];
    __shared__ float ssc[256];
    int t = threadIdx.x;
    if (t < 128){
        float mean = sums[t] / (float)NPIX;
        float var  = sums[128 + t] / (float)NPIX - mean * mean;
        float scale = g[t] * rsqrtf(var + EPS);
        ssc[t]       = scale;
        ssc[128 + t] = bb[t] - mean * scale;
    }
    int yrow = blockIdx.x % H, b = blockIdx.x / H;
    int rowbase = b * HW + yrow * W;
    const unsigned short* src = (const unsigned short*)yb;
    for (int it = 0; it < 64; it++){
        int idx = it * 256 + t;
        int c = idx & 127, px = idx >> 7;
        tile[px * 129 + c] = src[(size_t)(rowbase + px) * CO + c];
    }
    __syncthreads();
    for (int it = 0; it < 64; it++){
        int idx = it * 256 + t;
        int xw = idx & 127, o = idx >> 7;
        unsigned short u = tile[xw * 129 + o];
        float v = (float)(*(const __bf16*)&u);
        v = v * ssc[o] + ssc[128 + o];
        out[(((size_t)b * CO + o) * H + yrow) * W + xw] = v > 0.f ? v : 0.f;
    }
}

extern "C" void kernel_launch(void* const* d_in, const int* in_sizes, int n_in,
                              void* d_out, int out_size, void* d_ws, size_t ws_size,
                              hipStream_t stream){
    const float* x      = (const float*)d_in[0];
    const float* skip   = (const float*)d_in[1];
    const float* conv1w = (const float*)d_in[2];
    const float* bn1g   = (const float*)d_in[3];
    const float* bn1b   = (const float*)d_in[4];
    const float* offw   = (const float*)d_in[5];
    const float* offb   = (const float*)d_in[6];
    const float* defw   = (const float*)d_in[7];
    const float* defb   = (const float*)d_in[8];
    const float* bn2g   = (const float*)d_in[9];
    const float* bn2b   = (const float*)d_in[10];
    float* out = (float*)d_out;

    char* ws = (char*)d_ws;
    size_t off_bytes = 0;
    auto alloc = [&](size_t bytes) -> void* {
        void* p = ws + off_bytes;
        off_bytes += (bytes + 255) & ~(size_t)255;
        return p;
    };
    const size_t catp_elems = (size_t)NB * WP * WP * CCAT;
    const size_t hp_elems   = (size_t)NB * WP * WP * CO;
    bf16*  catp  = (bf16*) alloc(catp_elems * 2 + 2048);     // +tail pad for 2px overread
    bf16*  hp    = (bf16*) alloc(hp_elems * 2 + 2048);       // +tail pad for 2px overread
    bf16*  offs  = (bf16*) alloc((size_t)NPIX * 18 * 2);
    bf16*  yb    = (bf16*) alloc((size_t)NPIX * CO * 2);
    bf16*  wbt   = (bf16*) alloc((size_t)CO * K1 * 2 + 32768); // +pad: phase-54 prefetch overread
    bf16*  wob   = (bf16*) alloc((size_t)32 * KD * 2);
    bf16*  wdb   = (bf16*) alloc((size_t)CO * KD * 2);
    float* sums  = (float*)alloc(512 * 4);
    float* sums1 = sums;
    float* sums2 = sums + 256;

    k_prep<<<1024, 256, 0, stream>>>(sums, catp, hp);

    k_build_cat2<<<NB * H, 256, 0, stream>>>(x, skip, catp);

    const int ntr = CO * K1 + 32 * KD + CO * KD;
    k_tr_all<<<(ntr + 255) / 256, 256, 0, stream>>>(conv1w, offw, defw, wbt, wob, wdb);

    k_conv1_mfma<<<NB * H * 2, 256, 0, stream>>>(catp, wbt, hp, sums1);

    k_bn_apply_pad<<<(NPIX * CO + 255) / 256, 256, 0, stream>>>(hp, sums1, bn1g, bn1b);

    k_conv_off_mfma<<<NB * H * 2, 256, 0, stream>>>(hp, wob, offb, offs);

    k_deform_mfma<<<NB * H, 256, 0, stream>>>(hp, offs, wdb, defb, yb, sums2);

    k_final<<<NB * H, 256, 0, stream>>>(yb, sums2, bn2g, bn2b, out);
}

// Round 6
// 314.297 us; speedup vs baseline: 1.1825x; 1.0581x over previous
//
#include <hip/hip_runtime.h>
#include <hip/hip_bf16.h>

typedef __hip_bfloat16 bf16;
typedef __bf16 bf16x8 __attribute__((ext_vector_type(8)));
typedef __bf16 bf16x4 __attribute__((ext_vector_type(4)));
typedef float  f32x4  __attribute__((ext_vector_type(4)));

constexpr int NB   = 4;
constexpr int H    = 128;
constexpr int W    = 128;
constexpr int HW   = H * W;
constexpr int NPIX = NB * HW;        // 65536
constexpr int CCAT = 384;
constexpr int CSKIP= 128;
constexpr int CIN  = 256;
constexpr int CO   = 128;
constexpr int HS   = 64;
constexpr int WP   = 130;            // padded H/W
constexpr int K1   = 3456;           // conv1 GEMM K
constexpr int KD   = 1152;           // deform/off GEMM K
constexpr int NBORD= 2 * WP + 2 * (WP - 2);   // 516 border px per image
constexpr float EPS = 1e-5f;

constexpr int NTR  = CO * K1 + 32 * KD + CO * KD;   // 626688
constexpr int NCATB= NB * NBORD * CCAT;             // 792576
constexpr int NHPB = NB * NBORD * CO;               // 264192

__device__ __forceinline__ float b2f(bf16 v){ return __bfloat162float(v); }
__device__ __forceinline__ bf16  f2b(float v){ return __float2bfloat16(v); }

__device__ __forceinline__ void async_copy16(const void* g, void* s){
    __builtin_amdgcn_global_load_lds((const __attribute__((address_space(1))) void*)g,
                                     (__attribute__((address_space(3))) void*)s, 16, 0, 0);
}

// map border index 0..515 -> (y,x) on the WPxWP frame
__device__ __forceinline__ void border_yx(int p, int& y, int& x){
    if (p < WP)             { y = 0;        x = p; }
    else if (p < 2 * WP)    { y = WP - 1;   x = p - WP; }
    else if (p < 2 * WP + (WP - 2)) { y = p - 2 * WP + 1;          x = 0; }
    else                    { y = p - (2 * WP + (WP - 2)) + 1;     x = WP - 1; }
}

// ------------- k_setup: build_cat + weight transposes + border/stat zero -------------
// Blocks [0, NB*H): build cat interior rows (LDS transpose).
// Blocks [NB*H, ...): flat elementwise: [0,NTR) weights fragment-major;
// then 512 sums-zero; then catp borders; then hp borders.
__global__ __launch_bounds__(256) void k_setup(const float* __restrict__ x,
                                               const float* __restrict__ skip,
                                               const float* __restrict__ w1,
                                               const float* __restrict__ wo,
                                               const float* __restrict__ wd,
                                               float* __restrict__ sums,
                                               bf16* __restrict__ catp,
                                               bf16* __restrict__ hp,
                                               bf16* __restrict__ wt1,
                                               bf16* __restrict__ wto,
                                               bf16* __restrict__ wtd){
    constexpr int TS = 66;
    __shared__ bf16 tile[128 * TS];
    int t = threadIdx.x;

    if (blockIdx.x < NB * H){
        // ---- build cat interior ----
        int y  = blockIdx.x % H, b = blockIdx.x / H;
        int xx = t & 127, cp = t >> 7;

        float cy = (y * 63.0f) / 127.0f;
        int   y0 = (int)cy;
        int   y1 = min(y0 + 1, HS - 1);
        float wy = cy - y0;
        float cxf = (xx * 63.0f) / 127.0f;
        int   x0 = (int)cxf;
        int   x1 = min(x0 + 1, HS - 1);
        float wx = cxf - x0;

        bf16* orow = catp + (((size_t)b * WP + y + 1) * WP + 1) * CCAT;

        for (int chunk = 0; chunk < 6; chunk++){
            int cbase = chunk * 64;
            if (chunk >= 1) __syncthreads();
            if (chunk < 2){
                const float* sb = skip + ((size_t)(b * CSKIP + cbase + cp * 32) * H + y) * W;
#pragma unroll
                for (int i = 0; i < 32; i++)
                    tile[xx * TS + cp * 32 + i] = f2b(sb[(size_t)i * HW + xx]);
            } else {
                int icb = (chunk - 2) * 64 + cp * 32;
                const float* xr0 = x + ((size_t)(b * CIN + icb) * HS + y0) * HS;
                const float* xr1 = x + ((size_t)(b * CIN + icb) * HS + y1) * HS;
#pragma unroll
                for (int i = 0; i < 32; i++){
                    const float* r0 = xr0 + (size_t)i * HS * HS;
                    const float* r1 = xr1 + (size_t)i * HS * HS;
                    float v0 = r0[x0] * (1 - wx) + r0[x1] * wx;
                    float v1 = r1[x0] * (1 - wx) + r1[x1] * wx;
                    tile[xx * TS + cp * 32 + i] = f2b(v0 * (1 - wy) + v1 * wy);
                }
            }
            __syncthreads();
            int cc2 = (t & 31) * 2;
            int px0 = t >> 5;
#pragma unroll
            for (int pp = 0; pp < 16; pp++){
                int px = pp * 8 + px0;
                unsigned int v = *(const unsigned int*)&tile[px * TS + cc2];
                *(unsigned int*)&orow[(size_t)px * CCAT + cbase + cc2] = v;
            }
        }
        return;
    }

    int idx = (blockIdx.x - NB * H) * 256 + t;
    if (idx < NTR){
        int i = idx;
        if (i < CO * K1){
            // wt1: [p54][ks2][nb8][l64][e8]
            int e  = i & 7;
            int l  = (i >> 3) & 63;
            int nb = (i >> 9) & 7;
            int ks = (i >> 12) & 1;
            int p  = i >> 13;                 // 0..53
            int gp = p / 6, q = p - gp * 6;
            int ky = gp / 3, ci = gp - ky * 3;
            int kx = q >> 1, s64 = q & 1;
            int oc = nb * 16 + (l & 15);
            int ic = ci * 128 + s64 * 64 + ks * 32 + (l >> 4) * 8 + e;
            wt1[i] = f2b(w1[((oc * CCAT + ic) * 3 + ky) * 3 + kx]);
            return;
        }
        i -= CO * K1;
        if (i < 32 * KD){
            // wto: [kk9][s4][wn2][l64][e8]
            int e  = i & 7;
            int l  = (i >> 3) & 63;
            int wn = (i >> 9) & 1;
            int s  = (i >> 10) & 3;
            int kk = i >> 12;                 // 0..8
            int ky = kk / 3, kx = kk - ky * 3;
            int oc = wn * 16 + (l & 15);
            int ic = s * 32 + (l >> 4) * 8 + e;
            wto[i] = (oc < 18) ? f2b(wo[((oc * CO + ic) * 3 + ky) * 3 + kx]) : f2b(0.f);
            return;
        }
        i -= 32 * KD;
        // wtd: [kc18][ks2][wn2][ni4][l64][e8]
        int e  = i & 7;
        int l  = (i >> 3) & 63;
        int ni = (i >> 9) & 3;
        int wn = (i >> 11) & 1;
        int ks = (i >> 12) & 1;
        int kc = i >> 13;                 // 0..17
        int oc = wn * 64 + ni * 16 + (l & 15);
        int ic = (kc & 1) * 64 + ks * 32 + (l >> 4) * 8 + e;
        int kp = kc >> 1;
        wtd[i] = f2b(wd[(oc * CO + ic) * 9 + kp]);
        return;
    }
    idx -= NTR;
    if (idx < 512){ sums[idx] = 0.f; return; }
    idx -= 512;
    if (idx < NCATB){
        int c = idx % CCAT, r = idx / CCAT, p = r % NBORD, b = r / NBORD;
        int y, xw; border_yx(p, y, xw);
        catp[(((size_t)b * WP + y) * WP + xw) * CCAT + c] = f2b(0.f);
        return;
    }
    idx -= NCATB;
    if (idx < NHPB){
        int c = idx % CO, r = idx / CO, p = r % NBORD, b = r / NBORD;
        int y, xw; border_yx(p, y, xw);
        hp[(((size_t)b * WP + y) * WP + xw) * CO + c] = f2b(0.f);
    }
}

// ------------- conv1: A in LDS, B direct global->VGPR (fragment-major) -------------
// Swizzle key px&15 (was &7): a wave's 64 A-read lanes now span all 16 LDS
// 16B-slots -> conflict-free (was ~4 conflict-cy/read, 7.08M/dispatch).
__global__ __launch_bounds__(256) void k_conv1_mfma(const bf16* __restrict__ catp,
                                                    const bf16* __restrict__ wbt,
                                                    bf16* __restrict__ hp,
                                                    float* __restrict__ sums){
    __shared__ unsigned short Ab[2][68 * 128];   // 2 x 17408 B
    __shared__ float ps[256];
    int t = threadIdx.x;
    int l = t & 63, w = t >> 6;          // w = oc-slice (wn)
    int half = blockIdx.x & 1;
    int y = (blockIdx.x >> 1) % H, b = blockIdx.x / (2 * H);
    int px0 = half * 64;

    int m = l & 15, quad = l >> 4;

    f32x4 acc[4][2];
#pragma unroll
    for (int i = 0; i < 4; i++)
#pragma unroll
        for (int j = 0; j < 2; j++) acc[i][j] = f32x4{0.f, 0.f, 0.f, 0.f};

    const size_t rowStride = (size_t)WP * CCAT;
    const char* wq = (const char*)wbt + w * 2048 + l * 16;

    bf16x8 bA[2][2], bB[2][2];

    {
        const bf16* Arow = catp + ((size_t)(b * WP) + y) * rowStride + (size_t)px0 * CCAT;
        for (int i = w; i < 17; i += 4){
            int G = i * 64 + l;
            int px = G >> 4, ol = G & 15;
            int osrc = ol ^ (px & 15);
            async_copy16(Arow + (size_t)px * CCAT + osrc * 8, &Ab[0][i * 512]);
        }
#pragma unroll
        for (int ks = 0; ks < 2; ks++)
#pragma unroll
            for (int ni = 0; ni < 2; ni++)
                bA[ks][ni] = *(const bf16x8*)(wq + ks * 8192 + ni * 1024);
    }
    __syncthreads();

#pragma unroll 1
    for (int g = 0; g < 9; g++){
        if (g < 8){
            int gn = g + 1;
            int kyn = gn / 3, cin = gn - kyn * 3;
            const bf16* Arow = catp + ((size_t)(b * WP) + y + kyn) * rowStride
                             + (size_t)px0 * CCAT + cin * 128;
            for (int i = w; i < 17; i += 4){
                int G = i * 64 + l;
                int px = G >> 4, ol = G & 15;
                int osrc = ol ^ (px & 15);
                async_copy16(Arow + (size_t)px * CCAT + osrc * 8, &Ab[gn & 1][i * 512]);
            }
        }
        const bf16x8* ap = (const bf16x8*)&Ab[g & 1][0];
        const char* wg = wq + (size_t)g * 6 * 16384;
#pragma unroll
        for (int j = 0; j < 6; j++){
            int kx = j >> 1, s64 = j & 1;
            const char* wnx = wg + (j + 1) * 16384;
            if (j & 1){
#pragma unroll
                for (int ks = 0; ks < 2; ks++)
#pragma unroll
                    for (int ni = 0; ni < 2; ni++)
                        bA[ks][ni] = *(const bf16x8*)(wnx + ks * 8192 + ni * 1024);
            } else {
#pragma unroll
                for (int ks = 0; ks < 2; ks++)
#pragma unroll
                    for (int ni = 0; ni < 2; ni++)
                        bB[ks][ni] = *(const bf16x8*)(wnx + ks * 8192 + ni * 1024);
            }
#pragma unroll
            for (int ks = 0; ks < 2; ks++){
                int s = s64 * 2 + ks;
                bf16x8 af[4];
#pragma unroll
                for (int mi = 0; mi < 4; mi++){
                    int pxk = mi * 16 + m + kx;
                    af[mi] = ap[pxk * 16 + ((s * 4 + quad) ^ (pxk & 15))];
                }
                if (j & 1){
#pragma unroll
                    for (int mi = 0; mi < 4; mi++)
#pragma unroll
                        for (int ni = 0; ni < 2; ni++)
                            acc[mi][ni] = __builtin_amdgcn_mfma_f32_16x16x32_bf16(
                                af[mi], bB[ks][ni], acc[mi][ni], 0, 0, 0);
                } else {
#pragma unroll
                    for (int mi = 0; mi < 4; mi++)
#pragma unroll
                        for (int ni = 0; ni < 2; ni++)
                            acc[mi][ni] = __builtin_amdgcn_mfma_f32_16x16x32_bf16(
                                af[mi], bA[ks][ni], acc[mi][ni], 0, 0, 0);
                }
            }
        }
        __syncthreads();
    }

    size_t obase = (((size_t)b * WP + y + 1) * WP + 1 + px0) * CO;
#pragma unroll
    for (int mi = 0; mi < 4; mi++){
        int p0 = mi * 16 + quad * 4;
#pragma unroll
        for (int ni = 0; ni < 2; ni++){
            int oc = w * 32 + ni * 16 + m;
#pragma unroll
            for (int r = 0; r < 4; r++)
                hp[obase + (size_t)(p0 + r) * CO + oc] = f2b(acc[mi][ni][r]);
        }
    }
    ps[t] = 0.f;
    __syncthreads();
#pragma unroll
    for (int ni = 0; ni < 2; ni++){
        int ch = w * 32 + ni * 16 + m;
        float s = 0.f, q2 = 0.f;
#pragma unroll
        for (int mi = 0; mi < 4; mi++)
#pragma unroll
            for (int r = 0; r < 4; r++){
                float v = acc[mi][ni][r];
                s += v; q2 += v * v;
            }
        s += __shfl_xor(s, 16); s += __shfl_xor(s, 32);
        q2 += __shfl_xor(q2, 16); q2 += __shfl_xor(q2, 32);
        if (quad == 0){
            atomicAdd(&ps[ch], s);
            atomicAdd(&ps[128 + ch], q2);
        }
    }
    __syncthreads();
    if (t < 128){
        atomicAdd(&sums[t],       ps[t]);
        atomicAdd(&sums[128 + t], ps[128 + t]);
    }
}

// ------------- offset conv + BN1 fold + hq production -------------
// Reg-stages hp rows with BN1 scale/shift/relu applied (borders forced 0),
// writes the BN'd interior row to hq during ky==1 (each padded row 1..128 is
// exactly one block's ky==1 row). Eliminates the separate bn_apply pass.
__global__ __launch_bounds__(256) void k_conv_off_mfma(const bf16* __restrict__ hp,
                                                       const bf16* __restrict__ wob,
                                                       const float* __restrict__ off_b,
                                                       const float* __restrict__ sums,
                                                       const float* __restrict__ bn_g,
                                                       const float* __restrict__ bn_b,
                                                       bf16* __restrict__ offs,
                                                       bf16* __restrict__ hq){
    __shared__ unsigned short Ab[68 * 128];    // 17408 B
    __shared__ float2 ssc[128];
    int t = threadIdx.x, l = t & 63, w = t >> 6;
    if (t < 128){
        float mean = sums[t] / (float)NPIX;
        float var  = sums[128 + t] / (float)NPIX - mean * mean;
        float sc   = bn_g[t] * rsqrtf(var + EPS);
        ssc[t] = make_float2(sc, bn_b[t] - mean * sc);
    }
    int half = blockIdx.x & 1;
    int y = (blockIdx.x >> 1) % H, b = blockIdx.x / (2 * H);
    int px0 = half * 64;
    int m = l & 15, quad = l >> 4;
    int wm = w & 1, wn = w >> 1;

    f32x4 acc[2];
#pragma unroll
    for (int i = 0; i < 2; i++) acc[i] = f32x4{0.f, 0.f, 0.f, 0.f};

    const size_t rowStrideH = (size_t)WP * CO;
    const char* wq = (const char*)wob + wn * 1024 + l * 16;
    __syncthreads();                            // ssc ready

    for (int ky = 0; ky < 3; ky++){
        if (ky) __syncthreads();               // prior readers of Ab done
        int row = y + ky;                      // padded row 0..129
        const bf16* Arow = hp + ((size_t)(b * WP) + row) * rowStrideH
                         + (size_t)px0 * CO;
        bool rowborder = (row == 0) || (row == WP - 1);
        bf16* hqrow = hq + ((size_t)(b * WP) + row) * rowStrideH;
        for (int i = w; i < 17; i += 4){       // reg-stage + BN fold
            int G  = i * 64 + l;
            int px = G >> 4, ol = G & 15;
            int osrc = ol ^ (px & 15);
            int col = px0 + px;
            bool zero = rowborder || (col == 0) || (col >= WP - 1);
            bf16x8 raw = *(const bf16x8*)(Arow + (size_t)px * CO + osrc * 8);
            bf16x8 outv;
#pragma unroll
            for (int e = 0; e < 8; e++){
                float2 sb = ssc[osrc * 8 + e];
                float v = (float)raw[e] * sb.x + sb.y;
                v = v > 0.f ? v : 0.f;
                outv[e] = zero ? (__bf16)0.f : (__bf16)v;
            }
            *(bf16x8*)&Ab[G * 8] = outv;
            if (ky == 1 && col >= 1 && col <= 128)
                *(bf16x8*)(hqrow + (size_t)col * CO + osrc * 8) = outv;
        }
        bf16x8 bfr[3][4];                      // B frags for this ky (global)
#pragma unroll
        for (int kx = 0; kx < 3; kx++)
#pragma unroll
            for (int s = 0; s < 4; s++)
                bfr[kx][s] = *(const bf16x8*)(wq + (((ky * 3 + kx) * 4 + s) * 2048));
        __syncthreads();                       // staging visible
        const bf16x8* ap = (const bf16x8*)Ab;
        for (int kx = 0; kx < 3; kx++){
#pragma unroll
            for (int s = 0; s < 4; s++){
#pragma unroll
                for (int mi = 0; mi < 2; mi++){
                    int pxk = wm * 32 + mi * 16 + m + kx;
                    bf16x8 af = ap[pxk * 16 + ((s * 4 + quad) ^ (pxk & 15))];
                    acc[mi] = __builtin_amdgcn_mfma_f32_16x16x32_bf16(af, bfr[kx][s], acc[mi], 0, 0, 0);
                }
            }
        }
    }
    int oc = wn * 16 + m;
    if (oc < 18){
        float bias = off_b[oc];
        int rowpix = b * HW + y * W + px0;
#pragma unroll
        for (int mi = 0; mi < 2; mi++){
            int p0 = wm * 32 + mi * 16 + quad * 4;
#pragma unroll
            for (int r = 0; r < 4; r++)
                offs[(size_t)(rowpix + p0 + r) * 18 + oc] = f2b(acc[mi][r] + bias);
        }
    }
}

// ------------- deform: dbuf A-gen overlapped with MFMA, B global->VGPR -------------
// Gathers from hq (BN'd h, clamped-interior coords — borders never read).
__global__ __launch_bounds__(256) void k_deform_mfma(const bf16* __restrict__ hq,
                                                     const bf16* __restrict__ offs,
                                                     const bf16* __restrict__ wdb,
                                                     const float* __restrict__ def_b,
                                                     bf16* __restrict__ y,
                                                     float* __restrict__ sums){
    __shared__ unsigned short Ab[2][128 * 64];
    __shared__ int2   sc_yx[9 * 128];
    __shared__ float4 sc_w[9 * 128];
    __shared__ float  ps[256];

    int t = threadIdx.x, l = t & 63, w = t >> 6;
    int yrow = blockIdx.x % H, b = blockIdx.x / H;
    int rowpix = b * HW + yrow * W;

    for (int idx = t; idx < 9 * 128; idx += 256){
        int kp = idx >> 7, px = idx & 127;
        float dy = b2f(offs[(size_t)(rowpix + px) * 18 + 2 * kp]);
        float dx = b2f(offs[(size_t)(rowpix + px) * 18 + 2 * kp + 1]);
        float py = yrow + (kp / 3 - 1) + dy;
        float pxx = px + (kp % 3 - 1) + dx;
        float fy = floorf(py), fx = floorf(pxx);
        float wy = py - fy, wx = pxx - fx;
        int y0 = (int)fy, x0 = (int)fx;
        bool vy0 = (y0 >= 0) && (y0 < H);
        bool vy1 = (y0 + 1 >= 0) && (y0 + 1 < H);
        bool vx0 = (x0 >= 0) && (x0 < W);
        bool vx1 = (x0 + 1 >= 0) && (x0 + 1 < W);
        int y0c = min(max(y0, 0), H - 1),     y1c = min(max(y0 + 1, 0), H - 1);
        int x0c = min(max(x0, 0), W - 1),     x1c = min(max(x0 + 1, 0), W - 1);
        sc_yx[idx] = make_int2(((y0c + 1) * WP) | (((y1c + 1) * WP) << 16),
                               (x0c + 1) | ((x1c + 1) << 16));
        sc_w[idx] = make_float4((1 - wy) * (1 - wx) * (float)(vy0 && vx0),
                                (1 - wy) * wx       * (float)(vy0 && vx1),
                                wy * (1 - wx)       * (float)(vy1 && vx0),
                                wy * wx             * (float)(vy1 && vx1));
    }
    __syncthreads();

    int m = l & 15, quad = l >> 4;
    int wm = w & 1, wn = w >> 1;
    int g = l >> 4, j = l & 15;

    f32x4 acc[4][4];
#pragma unroll
    for (int i = 0; i < 4; i++)
#pragma unroll
        for (int jj = 0; jj < 4; jj++) acc[i][jj] = f32x4{0.f, 0.f, 0.f, 0.f};

    const bf16* hpb = hq + (size_t)b * WP * WP * CO;
    const char* wq = (const char*)wdb + wn * 4096 + l * 16;

    auto GEN = [&](int kc, unsigned short* dst){
        int kp = kc >> 1, ch = (kc & 1) * 64;
        int cb = ch + j * 4;
#pragma unroll
        for (int p = 0; p < 8; p++){
            int px = w * 32 + g * 8 + p;
            int idx = kp * 128 + px;
            int2 yx = sc_yx[idx];
            float4 w4 = sc_w[idx];
            int r0 = yx.x & 0xffff, r1 = ((unsigned)yx.x) >> 16;
            int c0 = yx.y & 0xffff, c1 = ((unsigned)yx.y) >> 16;
            const bf16* base = hpb + cb;
            bf16x4 s00 = *(const bf16x4*)(base + (size_t)(r0 + c0) * CO);
            bf16x4 s01 = *(const bf16x4*)(base + (size_t)(r0 + c1) * CO);
            bf16x4 s10 = *(const bf16x4*)(base + (size_t)(r1 + c0) * CO);
            bf16x4 s11 = *(const bf16x4*)(base + (size_t)(r1 + c1) * CO);
            bf16x4 pv;
#pragma unroll
            for (int r = 0; r < 4; r++){
                float v = w4.x * (float)s00[r] + w4.y * (float)s01[r]
                        + w4.z * (float)s10[r] + w4.w * (float)s11[r];
                pv[r] = (__bf16)v;
            }
            int oct_sw = (j >> 1) ^ (px & 7);
            *(bf16x4*)&dst[px * 64 + oct_sw * 8 + (j & 1) * 4] = pv;
        }
    };

    GEN(0, &Ab[0][0]);

#pragma unroll 1
    for (int kc = 0; kc < 18; kc++){
        __syncthreads();
        bf16x8 bfr[2][4];
        const char* wk = wq + (size_t)kc * 16384;
#pragma unroll
        for (int ks = 0; ks < 2; ks++)
#pragma unroll
            for (int ni = 0; ni < 4; ni++)
                bfr[ks][ni] = *(const bf16x8*)(wk + ks * 8192 + ni * 1024);
        if (kc < 17) GEN(kc + 1, &Ab[(kc + 1) & 1][0]);

        const bf16x8* ap = (const bf16x8*)&Ab[kc & 1][0];
#pragma unroll
        for (int ks = 0; ks < 2; ks++){
            bf16x8 af[4];
#pragma unroll
            for (int mi = 0; mi < 4; mi++){
                int px = wm * 64 + mi * 16 + m;
                af[mi] = ap[px * 8 + ((ks * 4 + quad) ^ (px & 7))];
            }
#pragma unroll
            for (int mi = 0; mi < 4; mi++)
#pragma unroll
                for (int ni = 0; ni < 4; ni++)
                    acc[mi][ni] = __builtin_amdgcn_mfma_f32_16x16x32_bf16(
                        af[mi], bfr[ks][ni], acc[mi][ni], 0, 0, 0);
        }
    }
#pragma unroll
    for (int mi = 0; mi < 4; mi++){
        int p0 = wm * 64 + mi * 16 + quad * 4;
#pragma unroll
        for (int ni = 0; ni < 4; ni++){
            int oc = wn * 64 + ni * 16 + m;
            float bias = def_b[oc];
#pragma unroll
            for (int r = 0; r < 4; r++)
                y[(size_t)(rowpix + p0 + r) * CO + oc] = f2b(acc[mi][ni][r] + bias);
        }
    }
    ps[t] = 0.f;
    __syncthreads();
#pragma unroll
    for (int ni = 0; ni < 4; ni++){
        int ch = wn * 64 + ni * 16 + m;
        float bias = def_b[ch];
        float s = 0.f, q = 0.f;
#pragma unroll
        for (int mi = 0; mi < 4; mi++)
#pragma unroll
            for (int r = 0; r < 4; r++){
                float v = acc[mi][ni][r] + bias;
                s += v; q += v * v;
            }
        s += __shfl_xor(s, 16); s += __shfl_xor(s, 32);
        q += __shfl_xor(q, 16); q += __shfl_xor(q, 32);
        if (quad == 0){
            atomicAdd(&ps[ch], s);
            atomicAdd(&ps[128 + ch], q);
        }
    }
    __syncthreads();
    if (t < 128){
        atomicAdd(&sums[t],       ps[t]);
        atomicAdd(&sums[128 + t], ps[128 + t]);
    }
}

// ------------- BN2 apply + relu + NHWC->NCHW (scale/shift inline) -------------
__global__ __launch_bounds__(256) void k_final(const bf16* __restrict__ yb,
                                               const float* __restrict__ sums,
                                               const float* __restrict__ g,
                                               const float* __restrict__ bb,
                                               float* __restrict__ out){
    __shared__ unsigned short tile[128 * 129];
    __shared__ float ssc[256];
    int t = threadIdx.x;
    if (t < 128){
        float mean = sums[t] / (float)NPIX;
        float var  = sums[128 + t] / (float)NPIX - mean * mean;
        float scale = g[t] * rsqrtf(var + EPS);
        ssc[t]       = scale;
        ssc[128 + t] = bb[t] - mean * scale;
    }
    int yrow = blockIdx.x % H, b = blockIdx.x / H;
    int rowbase = b * HW + yrow * W;
    const unsigned short* src = (const unsigned short*)yb;
    for (int it = 0; it < 64; it++){
        int idx = it * 256 + t;
        int c = idx & 127, px = idx >> 7;
        tile[px * 129 + c] = src[(size_t)(rowbase + px) * CO + c];
    }
    __syncthreads();
    for (int it = 0; it < 64; it++){
        int idx = it * 256 + t;
        int xw = idx & 127, o = idx >> 7;
        unsigned short u = tile[xw * 129 + o];
        float v = (float)(*(const __bf16*)&u);
        v = v * ssc[o] + ssc[128 + o];
        out[(((size_t)b * CO + o) * H + yrow) * W + xw] = v > 0.f ? v : 0.f;
    }
}

extern "C" void kernel_launch(void* const* d_in, const int* in_sizes, int n_in,
                              void* d_out, int out_size, void* d_ws, size_t ws_size,
                              hipStream_t stream){
    const float* x      = (const float*)d_in[0];
    const float* skip   = (const float*)d_in[1];
    const float* conv1w = (const float*)d_in[2];
    const float* bn1g   = (const float*)d_in[3];
    const float* bn1b   = (const float*)d_in[4];
    const float* offw   = (const float*)d_in[5];
    const float* offb   = (const float*)d_in[6];
    const float* defw   = (const float*)d_in[7];
    const float* defb   = (const float*)d_in[8];
    const float* bn2g   = (const float*)d_in[9];
    const float* bn2b   = (const float*)d_in[10];
    float* out = (float*)d_out;

    char* ws = (char*)d_ws;
    size_t off_bytes = 0;
    auto alloc = [&](size_t bytes) -> void* {
        void* p = ws + off_bytes;
        off_bytes += (bytes + 255) & ~(size_t)255;
        return p;
    };
    const size_t catp_elems = (size_t)NB * WP * WP * CCAT;
    const size_t hp_elems   = (size_t)NB * WP * WP * CO;
    bf16*  catp  = (bf16*) alloc(catp_elems * 2 + 2048);     // +tail pad for 2px overread
    bf16*  hp    = (bf16*) alloc(hp_elems * 2 + 2048);       // raw conv1 output
    bf16*  hq    = (bf16*) alloc(hp_elems * 2 + 2048);       // BN'd h (interior)
    bf16*  offs  = (bf16*) alloc((size_t)NPIX * 18 * 2);
    bf16*  yb    = (bf16*) alloc((size_t)NPIX * CO * 2);
    bf16*  wbt   = (bf16*) alloc((size_t)CO * K1 * 2 + 32768); // +pad: phase-54 prefetch overread
    bf16*  wob   = (bf16*) alloc((size_t)32 * KD * 2);
    bf16*  wdb   = (bf16*) alloc((size_t)CO * KD * 2);
    float* sums  = (float*)alloc(512 * 4);
    float* sums1 = sums;
    float* sums2 = sums + 256;

    const int nflat = NTR + 512 + NCATB + NHPB;
    const int setup_blocks = NB * H + (nflat + 255) / 256;

    k_setup<<<setup_blocks, 256, 0, stream>>>(x, skip, conv1w, offw, defw,
                                              sums, catp, hp, wbt, wob, wdb);

    k_conv1_mfma<<<NB * H * 2, 256, 0, stream>>>(catp, wbt, hp, sums1);

    k_conv_off_mfma<<<NB * H * 2, 256, 0, stream>>>(hp, wob, offb, sums1,
                                                    bn1g, bn1b, offs, hq);

    k_deform_mfma<<<NB * H, 256, 0, stream>>>(hq, offs, wdb, defb, yb, sums2);

    k_final<<<NB * H, 256, 0, stream>>>(yb, sums2, bn2g, bn2b, out);
}